// Round 2
// baseline (33768.341 us; speedup 1.0000x reference)
//
#include <hip/hip_runtime.h>
#include <cstdint>
#include <cstddef>

// ---------------------------------------------------------------------------
// VWFutureModel: 2-layer GRU (TF GRUCell) scan over T=128, N=256, C=64, U=512
// + fused dense head: elu(ys @ Wh + bh) @ Wp + bp -> out [N,T,C] fp32.
//
// R2: same fp32 persistent design as R1, hardened against hangs:
//  - hipLaunchCooperativeKernel (validates co-residency; error != deadlock)
//  - __launch_bounds__(512, 2): VGPR <= 256 so an 8-wave WG is schedulable
//  - bounded spin in the grid barrier (timeout -> wrong answer, not a hang)
// 256 WGs x 512 thr; 2D partition 8 m-groups (32 rows) x 32 n-slices;
// 3 grid barriers per step; dense head pipelined 1 step behind the scan.
// ---------------------------------------------------------------------------

#define NWG 256
#define TPB 512

constexpr int N_ = 256, T_ = 128, C_ = 64, U_ = 512, H_ = 256;

// workspace layout in floats
constexpr size_t SZ_H    = (size_t)N_ * U_;            // 131072
constexpr size_t OFF_H1  = 0;                          // 2 buffers
constexpr size_t OFF_H2  = OFF_H1 + 2 * SZ_H;          // 262144
constexpr size_t OFF_BAR = OFF_H2 + 2 * SZ_H;          // 524288 (64 floats)
constexpr size_t OFF_G1  = OFF_BAR + 64;               // 524352, N x 1024
constexpr size_t OFF_G2  = OFF_G1 + (size_t)N_ * 1024; // 786496, N x 1024
constexpr size_t OFF_HID = OFF_G2 + (size_t)N_ * 1024; // 1048640, N x 256
constexpr size_t WS_FLOATS = OFF_HID + (size_t)N_ * H_;

constexpr int LDP = 257;  // LDS row pitch (256 + 1 pad: conflict-free reads)

__device__ __forceinline__ float sigmoidf_(float z) {
  return 1.0f / (1.0f + __expf(-z));
}
__device__ __forceinline__ float tanhf_(float z) {
  // 1 - 2/(1+e^{2z}) : exact at +-inf
  return 1.0f - 2.0f / (1.0f + __expf(2.0f * z));
}

// Sense-reversing grid barrier. bar[0]=count, bar[32]=epoch (128B apart).
// Bounded spin: if the barrier wedges, we fall through (answer goes wrong,
// bench reports absmax failure) instead of hanging the GPU.
__device__ __forceinline__ void gbar(unsigned* bar) {
  __syncthreads();
  if (threadIdx.x == 0) {
    __threadfence();  // release
    unsigned e = __hip_atomic_load(bar + 32, __ATOMIC_RELAXED, __HIP_MEMORY_SCOPE_AGENT);
    unsigned a = __hip_atomic_fetch_add(bar, 1u, __ATOMIC_ACQ_REL, __HIP_MEMORY_SCOPE_AGENT);
    if (a == NWG - 1) {
      __hip_atomic_store(bar, 0u, __ATOMIC_RELAXED, __HIP_MEMORY_SCOPE_AGENT);
      __hip_atomic_store(bar + 32, e + 1u, __ATOMIC_RELEASE, __HIP_MEMORY_SCOPE_AGENT);
    } else {
      unsigned spins = 0;
      while (__hip_atomic_load(bar + 32, __ATOMIC_RELAXED, __HIP_MEMORY_SCOPE_AGENT) == e) {
        __builtin_amdgcn_s_sleep(8);
        if (++spins > (1u << 18)) break;  // ~100ms escape hatch
      }
    }
    __threadfence();  // acquire
  }
  __syncthreads();
}

// Stage 32 rows x CK cols of A into LDS. 512 threads. Optional elementwise
// gate multiply (for r*h terms). Sources are row-major fp32.
template <int CK, bool GATED>
__device__ __forceinline__ void stage(float (*lds)[LDP],
                                      const float* __restrict__ src, int sStride, int sOff,
                                      const float* __restrict__ gate, int gStride, int gOff,
                                      int row0) {
  constexpr int PER = CK / 16;  // floats per thread: 16 (CK=256) or 4 (CK=64)
  const int r  = threadIdx.x >> 4;          // 0..31
  const int c0 = (threadIdx.x & 15) * PER;  // col start
  const float* s = src + (size_t)(row0 + r) * sStride + sOff + c0;
  float4 a0, a1, a2, a3;
  a0 = *(const float4*)(s);
  if constexpr (PER >= 8)  a1 = *(const float4*)(s + 4);
  if constexpr (PER >= 16) { a2 = *(const float4*)(s + 8); a3 = *(const float4*)(s + 12); }
  if constexpr (GATED) {
    const float* g = gate + (size_t)(row0 + r) * gStride + gOff + c0;
    float4 g0 = *(const float4*)(g);
    a0.x *= g0.x; a0.y *= g0.y; a0.z *= g0.z; a0.w *= g0.w;
    if constexpr (PER >= 8) {
      float4 g1v = *(const float4*)(g + 4);
      a1.x *= g1v.x; a1.y *= g1v.y; a1.z *= g1v.z; a1.w *= g1v.w;
    }
    if constexpr (PER >= 16) {
      float4 g2v = *(const float4*)(g + 8);
      float4 g3v = *(const float4*)(g + 12);
      a2.x *= g2v.x; a2.y *= g2v.y; a2.z *= g2v.z; a2.w *= g2v.w;
      a3.x *= g3v.x; a3.y *= g3v.y; a3.z *= g3v.z; a3.w *= g3v.w;
    }
  }
  float* d = &lds[r][c0];
  d[0] = a0.x; d[1] = a0.y; d[2] = a0.z; d[3] = a0.w;
  if constexpr (PER >= 8)  { d[4] = a1.x; d[5] = a1.y; d[6] = a1.z; d[7] = a1.w; }
  if constexpr (PER >= 16) {
    d[8]  = a2.x; d[9]  = a2.y; d[10] = a2.z; d[11] = a2.w;
    d[12] = a3.x; d[13] = a3.y; d[14] = a3.z; d[15] = a3.w;
  }
}

template <int CK>
__device__ __forceinline__ void fma2(float2& acc, const float (*lds)[LDP], int row,
                                     const float* __restrict__ B, int ldB) {
#pragma unroll 8
  for (int k = 0; k < CK; ++k) {
    const float a = lds[row][k];
    const float2 b = *(const float2*)(B + (size_t)k * ldB);
    acc.x = fmaf(a, b.x, acc.x);
    acc.y = fmaf(a, b.y, acc.y);
  }
}

template <int CK>
__device__ __forceinline__ void fma1(float& acc, const float (*lds)[LDP], int row,
                                     const float* __restrict__ B, int ldB) {
#pragma unroll 8
  for (int k = 0; k < CK; ++k) {
    acc = fmaf(lds[row][k], B[(size_t)k * ldB], acc);
  }
}

extern "C" __global__ __launch_bounds__(TPB, 2)
void gru_persistent(const float* __restrict__ frames,
                    const float* __restrict__ Wg1, const float* __restrict__ bg1,
                    const float* __restrict__ Wc1, const float* __restrict__ bc1,
                    const float* __restrict__ Wg2, const float* __restrict__ bg2,
                    const float* __restrict__ Wc2, const float* __restrict__ bc2,
                    const float* __restrict__ Wh,  const float* __restrict__ bh,
                    const float* __restrict__ Wp,  const float* __restrict__ bp,
                    float* __restrict__ out, float* __restrict__ ws) {
  __shared__ float lds[32][LDP];

  float* h1b = ws + OFF_H1;
  float* h2b = ws + OFF_H2;
  unsigned* bar = (unsigned*)(ws + OFF_BAR);
  float* g1  = ws + OFF_G1;
  float* g2  = ws + OFF_G2;
  float* hid = ws + OFF_HID;

  const int tid  = threadIdx.x;
  const int wg   = blockIdx.x;
  // XCD-aware mapping (perf heuristic only): wgs dispatched round-robin over
  // 8 XCDs; give each XCD 4 contiguous n-slices so its L2 weight set ~1.2MB.
  const int xcd   = wg & 7;
  const int grp   = wg >> 3;               // 0..31
  const int m_blk = grp >> 2;              // 0..7
  const int n_blk = (xcd << 2) | (grp & 3);// 0..31
  const int row0  = m_blk * 32;

  const int rowA = tid & 31;   // output row within tile
  const int cq   = tid >> 5;   // 0..15
  const int nrow = row0 + rowA;

  for (int t = 0; t <= T_; ++t) {
    const int p = t & 1;
    const float* h1o = h1b + (size_t)p * SZ_H;
    float*       h1n = h1b + (size_t)(p ^ 1) * SZ_H;
    const float* h2o = h2b + (size_t)p * SZ_H;
    float*       h2n = h2b + (size_t)(p ^ 1) * SZ_H;

    // -------- P1: gates1 = sigmoid([x, h1] @ Wg1 + bg1) -> g1 --------
    if (t < T_) {
      float2 acc = {0.f, 0.f};
      const int col = n_blk * 32 + cq * 2;  // 0..1023
      stage<64, false>(lds, frames, T_ * C_, t * C_, nullptr, 0, 0, row0);
      __syncthreads();
      fma2<64>(acc, lds, rowA, Wg1 + col, 1024);
      __syncthreads();
#pragma unroll 1
      for (int ch = 0; ch < 2; ++ch) {
        stage<256, false>(lds, h1o, U_, ch * 256, nullptr, 0, 0, row0);
        __syncthreads();
        fma2<256>(acc, lds, rowA, Wg1 + (size_t)(64 + ch * 256) * 1024 + col, 1024);
        __syncthreads();
      }
      const float2 bb = *(const float2*)(bg1 + col);
      float* gp = g1 + (size_t)nrow * 1024 + col;
      gp[0] = sigmoidf_(acc.x + bb.x);
      gp[1] = sigmoidf_(acc.y + bb.y);
    }
    gbar(bar);

    // -------- P2: c1 = tanh([x, r1*h1] @ Wc1 + bc1); h1' = u1*h1+(1-u1)*c1
    if (t < T_) {
      float acc = 0.f;
      const int col = n_blk * 16 + cq;  // 0..511
      stage<64, false>(lds, frames, T_ * C_, t * C_, nullptr, 0, 0, row0);
      __syncthreads();
      fma1<64>(acc, lds, rowA, Wc1 + col, U_);
      __syncthreads();
#pragma unroll 1
      for (int ch = 0; ch < 2; ++ch) {
        stage<256, true>(lds, h1o, U_, ch * 256, g1, 1024, ch * 256, row0);
        __syncthreads();
        fma1<256>(acc, lds, rowA, Wc1 + (size_t)(64 + ch * 256) * U_ + col, U_);
        __syncthreads();
      }
      const float cv = tanhf_(acc + bc1[col]);
      const float u  = g1[(size_t)nrow * 1024 + 512 + col];
      const float ho = h1o[(size_t)nrow * U_ + col];
      h1n[(size_t)nrow * U_ + col] = u * ho + (1.f - u) * cv;
    }
    // -------- P2b: hidden(t-1) = elu(h2[p] @ Wh + bh) (h2[p] = h2new(t-1))
    if (t > 0) {
      float acc = 0.f;
      const int col = n_blk * 8 + (cq & 7);  // 0..255
      const bool act = tid < 256;
#pragma unroll 1
      for (int ch = 0; ch < 2; ++ch) {
        stage<256, false>(lds, h2o, U_, ch * 256, nullptr, 0, 0, row0);
        __syncthreads();
        if (act) fma1<256>(acc, lds, rowA, Wh + (size_t)(ch * 256) * H_ + col, H_);
        __syncthreads();
      }
      if (act) {
        const float z = acc + bh[col];
        hid[(size_t)nrow * H_ + col] = z > 0.f ? z : __expf(z) - 1.f;
      }
    }
    gbar(bar);

    // -------- P3: gates2 = sigmoid([h1', h2] @ Wg2 + bg2) -> g2 --------
    if (t < T_) {
      float2 acc = {0.f, 0.f};
      const int col = n_blk * 32 + cq * 2;  // 0..1023
#pragma unroll 1
      for (int ch = 0; ch < 4; ++ch) {
        const float* src = (ch < 2) ? h1n : h2o;
        stage<256, false>(lds, src, U_, (ch & 1) * 256, nullptr, 0, 0, row0);
        __syncthreads();
        fma2<256>(acc, lds, rowA, Wg2 + (size_t)(ch * 256) * 1024 + col, 1024);
        __syncthreads();
      }
      const float2 bb = *(const float2*)(bg2 + col);
      float* gp = g2 + (size_t)nrow * 1024 + col;
      gp[0] = sigmoidf_(acc.x + bb.x);
      gp[1] = sigmoidf_(acc.y + bb.y);
    }
    gbar(bar);

    // -------- P4: c2 = tanh([h1', r2*h2] @ Wc2 + bc2); h2' update --------
    if (t < T_) {
      float acc = 0.f;
      const int col = n_blk * 16 + cq;  // 0..511
#pragma unroll 1
      for (int ch = 0; ch < 4; ++ch) {
        if (ch < 2) stage<256, false>(lds, h1n, U_, (ch & 1) * 256, nullptr, 0, 0, row0);
        else        stage<256, true >(lds, h2o, U_, (ch & 1) * 256, g2, 1024, (ch & 1) * 256, row0);
        __syncthreads();
        fma1<256>(acc, lds, rowA, Wc2 + (size_t)(ch * 256) * U_ + col, U_);
        __syncthreads();
      }
      const float cv = tanhf_(acc + bc2[col]);
      const float u  = g2[(size_t)nrow * 1024 + 512 + col];
      const float ho = h2o[(size_t)nrow * U_ + col];
      h2n[(size_t)nrow * U_ + col] = u * ho + (1.f - u) * cv;
    }
    // -------- P4b: out[:, t-1, :] = hid @ Wp + bp --------
    if (t > 0) {
      if (tid < 64) {
        float acc = 0.f;
        const int col = n_blk * 2 + cq;  // cq in {0,1} since tid<64 -> col 0..63
        const float* hrow = hid + (size_t)nrow * H_;
#pragma unroll 8
        for (int k = 0; k < H_; ++k) {
          acc = fmaf(hrow[k], Wp[(size_t)k * C_ + col], acc);
        }
        out[(size_t)nrow * (T_ * C_) + (size_t)(t - 1) * C_ + col] = acc + bp[col];
      }
    }
  }
}

extern "C" void kernel_launch(void* const* d_in, const int* in_sizes, int n_in,
                              void* d_out, int out_size, void* d_ws, size_t ws_size,
                              hipStream_t stream) {
  const float* frames = (const float*)d_in[0];
  const float* Wg1 = (const float*)d_in[1];
  const float* bg1 = (const float*)d_in[2];
  const float* Wc1 = (const float*)d_in[3];
  const float* bc1 = (const float*)d_in[4];
  const float* Wg2 = (const float*)d_in[5];
  const float* bg2 = (const float*)d_in[6];
  const float* Wc2 = (const float*)d_in[7];
  const float* bc2 = (const float*)d_in[8];
  const float* Wh  = (const float*)d_in[9];
  const float* bh  = (const float*)d_in[10];
  const float* Wp  = (const float*)d_in[11];
  const float* bp  = (const float*)d_in[12];
  float* out = (float*)d_out;
  float* ws  = (float*)d_ws;

  // zero h1 (2 bufs), h2 (2 bufs), barrier state each call (deterministic)
  hipMemsetAsync(d_ws, 0, OFF_G1 * sizeof(float), stream);

  void* args[] = {(void*)&frames, (void*)&Wg1, (void*)&bg1, (void*)&Wc1, (void*)&bc1,
                  (void*)&Wg2, (void*)&bg2, (void*)&Wc2, (void*)&bc2,
                  (void*)&Wh, (void*)&bh, (void*)&Wp, (void*)&bp,
                  (void*)&out, (void*)&ws};
  hipError_t err = hipLaunchCooperativeKernel((const void*)gru_persistent,
                                              dim3(NWG), dim3(TPB), args, 0, stream);
  if (err != hipSuccess) {
    (void)hipGetLastError();  // clear error state
    hipLaunchKernelGGL(gru_persistent, dim3(NWG), dim3(TPB), 0, stream,
                       frames, Wg1, bg1, Wc1, bc1, Wg2, bg2, Wc2, bc2,
                       Wh, bh, Wp, bp, out, ws);
  }
}

// Round 3
// 12808.276 us; speedup vs baseline: 2.6364x; 2.6364x over previous
//
#include <hip/hip_runtime.h>
#include <cstdint>
#include <cstddef>

// ---------------------------------------------------------------------------
// VWFutureModel: 2-layer GRU scan (T=128, N=256, C=64, U=512) + dense head.
// R3: split-bf16 MFMA persistent kernel.
//  - weights pre-swizzled per launch into per-WG fragment streams (ws)
//  - activations kept as global bf16 hi/lo planes; A-frags loaded directly
//  - 3 chained mfma_f32_16x16x32_bf16 per chunk (hi*hi + hi*lo + lo*hi)
//  - per-m-group (32 WG) barriers instead of grid barriers (row-local deps)
//  - LDS f32 k-split reduction, deterministic order
//  - fallback to proven R2 fp32 kernel if ws_size too small
// ---------------------------------------------------------------------------

#define NWG 256
#define TPB 512

constexpr int N_ = 256, T_ = 128, C_ = 64, U_ = 512, H_ = 256;

typedef __attribute__((ext_vector_type(8))) short short8;
typedef __attribute__((ext_vector_type(4))) float f32x4;

// ---------------- byte offsets in workspace (new kernel) -------------------
constexpr size_t HPB      = 262144;                 // one h plane: 256*512*2B
constexpr size_t OFF_BAR  = 0;                      // 2048 B barrier area
constexpr size_t OFF_HP   = 2048;                   // 2 bufs x [h1hi,h1lo,h2hi,h2lo]
constexpr size_t OFF_RH1  = OFF_HP + 8 * HPB;       // rh1 hi,lo (2*262144)
constexpr size_t OFF_RH2  = OFF_RH1 + 524288;
constexpr size_t OFF_G1U  = OFF_RH2 + 524288;       // fp32 [256][512]
constexpr size_t OFF_G2U  = OFF_G1U + 524288;
constexpr size_t OFF_HID  = OFF_G2U + 524288;       // hid hi,lo (2*131072)
constexpr size_t OFF_XHI  = OFF_HID + 262144;       // [256][8192] bf16
constexpr size_t OFF_XLO  = OFF_XHI + 4194304;
constexpr size_t OFF_WG1S = OFF_XLO + 4194304;      // 32 * 81920
constexpr size_t OFF_WC1S = OFF_WG1S + 32 * 81920;  // 32 * 40960
constexpr size_t OFF_WG2S = OFF_WC1S + 32 * 40960;  // 32 * 131072
constexpr size_t OFF_WC2S = OFF_WG2S + 32 * 131072; // 32 * 65536
constexpr size_t OFF_WHS  = OFF_WC2S + 32 * 65536;  // 16 * 32768
constexpr size_t OFF_WPS  = OFF_WHS + 16 * 32768;   // 4 * 16384
constexpr size_t WS_NEED  = OFF_WPS + 4 * 16384;    // ~23.7 MB

// ---------------- helpers --------------------------------------------------
__device__ __forceinline__ float sigmoidf_(float z) {
  return 1.0f / (1.0f + __expf(-z));
}
__device__ __forceinline__ float tanhf_(float z) {
  return 1.0f - 2.0f / (1.0f + __expf(2.0f * z));
}
__device__ __forceinline__ unsigned short bf_hi(float f) {
  unsigned int x = __float_as_uint(f);
  unsigned int r = x + 0x7FFFu + ((x >> 16) & 1u);
  return (unsigned short)(r >> 16);
}
__device__ __forceinline__ float bf_f(unsigned short h) {
  return __uint_as_float(((unsigned int)h) << 16);
}
__device__ __forceinline__ unsigned short bf_lo(float f, unsigned short hi) {
  return bf_hi(f - bf_f(hi));
}
__device__ __forceinline__ short8 ld8(const unsigned short* p) {
  union { uint4 u; short8 s; } x;
  x.u = *(const uint4*)p;
  return x.s;
}

// barrier: count at b[0], epoch at b[16]; np participants; bounded spin.
__device__ __forceinline__ void gbarN(unsigned* b, unsigned np) {
  __syncthreads();
  if (threadIdx.x == 0) {
    __threadfence();
    unsigned e = __hip_atomic_load(b + 16, __ATOMIC_RELAXED, __HIP_MEMORY_SCOPE_AGENT);
    unsigned a = __hip_atomic_fetch_add(b, 1u, __ATOMIC_ACQ_REL, __HIP_MEMORY_SCOPE_AGENT);
    if (a == np - 1) {
      __hip_atomic_store(b, 0u, __ATOMIC_RELAXED, __HIP_MEMORY_SCOPE_AGENT);
      __hip_atomic_store(b + 16, e + 1u, __ATOMIC_RELEASE, __HIP_MEMORY_SCOPE_AGENT);
    } else {
      unsigned spins = 0;
      while (__hip_atomic_load(b + 16, __ATOMIC_RELAXED, __HIP_MEMORY_SCOPE_AGENT) == e) {
        __builtin_amdgcn_s_sleep(1);
        if (++spins > (1u << 20)) break;  // escape hatch: fail, don't hang
      }
    }
    __threadfence();
  }
  __syncthreads();
}

// write one weight fragment stream (per consumer ordering) -----------------
__device__ void writeStream(const float* __restrict__ W, int ldW, int colbase,
                            char* sb, int nsplit, int slots, int tnn, int nch) {
  const int tid = threadIdx.x;
  const int lane = tid & 63;
  const int e = tid >> 6;  // 0..7
  const int nf = nsplit * slots * tnn;
  for (int f = 0; f < nf; ++f) {
    int tn = f % tnn;
    int ci = (f / tnn) % slots;
    int ks = f / (tnn * slots);
    int c = ks + ci * nsplit;
    if (c >= nch) continue;
    int k = 32 * c + ((lane >> 4) << 3) + e;
    int col = colbase + 16 * tn + (lane & 15);
    float v = W[(size_t)k * ldW + col];
    unsigned short hi = bf_hi(v);
    unsigned short lo = bf_lo(v, hi);
    unsigned short* fb = (unsigned short*)(sb + (size_t)f * 2048);
    fb[lane * 8 + e] = hi;
    fb[512 + lane * 8 + e] = lo;
  }
}

// MFMA phase: TM row-tiles x TN col-tiles, K split NSPLIT ways over 8 waves.
// Writes per-(tile,ksub) partials to red[], syncs.
template <int TM, int TN, int NSPLIT, int NCH, int SLOTS, int KA>
__device__ __forceinline__ void mm_phase(
    const unsigned short* __restrict__ A1h, const unsigned short* __restrict__ A1l,
    int lda1, int aoff,
    const unsigned short* __restrict__ A2h, const unsigned short* __restrict__ A2l,
    int lda2, const char* __restrict__ bstr, float* red, int row0loc) {
  const int tid = threadIdx.x;
  const int ww = tid >> 6, lane = tid & 63;
  const int tm = ww / NSPLIT;
  const int ks = ww % NSPLIT;
  __syncthreads();  // protect red reuse from previous phase reads
  f32x4 acc0[TN], acc1[TN], acc2[TN];
#pragma unroll
  for (int tn = 0; tn < TN; ++tn) {
    acc0[tn] = (f32x4){0.f, 0.f, 0.f, 0.f};
    acc1[tn] = (f32x4){0.f, 0.f, 0.f, 0.f};
    acc2[tn] = (f32x4){0.f, 0.f, 0.f, 0.f};
  }
  const int arow = row0loc + 16 * tm + (lane & 15);
  const int kgrp = (lane >> 4) << 3;
#pragma unroll 2
  for (int ci = 0; ci < SLOTS; ++ci) {
    int c = ks + ci * NSPLIT;
    if (c >= NCH) break;
    int ak = 32 * c + kgrp;
    const unsigned short *ph, *pl;
    if (ak < KA) {
      ph = A1h + (size_t)arow * lda1 + aoff + ak;
      pl = A1l + (size_t)arow * lda1 + aoff + ak;
    } else {
      int ak2 = ak - KA;
      ph = A2h + (size_t)arow * lda2 + ak2;
      pl = A2l + (size_t)arow * lda2 + ak2;
    }
    short8 Ah = ld8(ph);
    short8 Al = ld8(pl);
    const char* fb = bstr + ((size_t)(ks * SLOTS + ci) * TN) * 2048;
#pragma unroll
    for (int tn = 0; tn < TN; ++tn) {
      short8 Bh = ld8((const unsigned short*)(fb + (size_t)tn * 2048) + lane * 8);
      short8 Bl = ld8((const unsigned short*)(fb + (size_t)tn * 2048 + 1024) + lane * 8);
      acc0[tn] = __builtin_amdgcn_mfma_f32_16x16x32_bf16(Ah, Bh, acc0[tn], 0, 0, 0);
      acc1[tn] = __builtin_amdgcn_mfma_f32_16x16x32_bf16(Ah, Bl, acc1[tn], 0, 0, 0);
      acc2[tn] = __builtin_amdgcn_mfma_f32_16x16x32_bf16(Al, Bh, acc2[tn], 0, 0, 0);
    }
  }
#pragma unroll
  for (int tn = 0; tn < TN; ++tn) {
    f32x4 s = acc0[tn] + acc1[tn] + acc2[tn];
    int slot = (tm * TN + tn) * NSPLIT + ks;
    *(f32x4*)(&red[slot * 256 + lane * 4]) = s;
  }
  __syncthreads();
}

// reduce partials + run epilogue lambda per output element
template <int TM, int TN, int NSPLIT, typename F>
__device__ __forceinline__ void epi(const float* red, int row0loc, int col0, F f) {
  for (int idx = threadIdx.x; idx < TM * TN * 256; idx += TPB) {
    int tg = idx >> 8, e = idx & 255;
    float z = 0.f;
#pragma unroll
    for (int s = 0; s < NSPLIT; ++s) z += red[(tg * NSPLIT + s) * 256 + e];
    int tm = tg / TN, tn = tg % TN;
    int le = e >> 2, j = e & 3;
    int row = row0loc + 16 * tm + ((le >> 4) << 2) + j;
    int col = col0 + 16 * tn + (le & 15);
    f(row, col, z);
  }
}

// ---------------- new MFMA kernel ------------------------------------------
extern "C" __global__ __launch_bounds__(TPB, 2)
void gru_mfma(const float* __restrict__ frames,
              const float* __restrict__ Wg1, const float* __restrict__ bg1,
              const float* __restrict__ Wc1, const float* __restrict__ bc1,
              const float* __restrict__ Wg2, const float* __restrict__ bg2,
              const float* __restrict__ Wc2, const float* __restrict__ bc2,
              const float* __restrict__ Wh,  const float* __restrict__ bh,
              const float* __restrict__ Wp,  const float* __restrict__ bp,
              float* __restrict__ out, char* __restrict__ wsb) {
  __shared__ float red[4096];  // 16 KB: up to 16 partial tiles of 256 f32

  const int tid = threadIdx.x;
  const int wg = blockIdx.x;
  const int xcd = wg & 7;
  const int grp = wg >> 3;
  const int m = grp >> 2;                 // 0..7  (row group: rows 32m..32m+31)
  const int n = (xcd << 2) | (grp & 3);   // 0..31 (col slice; also lid in group)
  const int row0 = m * 32;

  unsigned* barw = (unsigned*)(wsb + OFF_BAR);
  unsigned* gb = barw + m * 32;    // per-group barrier
  unsigned* allb = barw + 256;     // global barrier (prologue only)

  unsigned short* xhi = (unsigned short*)(wsb + OFF_XHI);
  unsigned short* xlo = (unsigned short*)(wsb + OFF_XLO);
  unsigned short* rh1hi = (unsigned short*)(wsb + OFF_RH1);
  unsigned short* rh1lo = (unsigned short*)(wsb + OFF_RH1 + 262144);
  unsigned short* rh2hi = (unsigned short*)(wsb + OFF_RH2);
  unsigned short* rh2lo = (unsigned short*)(wsb + OFF_RH2 + 262144);
  float* g1u = (float*)(wsb + OFF_G1U);
  float* g2u = (float*)(wsb + OFF_G2U);
  unsigned short* hidhi = (unsigned short*)(wsb + OFF_HID);
  unsigned short* hidlo = (unsigned short*)(wsb + OFF_HID + 131072);

  // ---- prologue: x planes ----
  {
    const size_t base = (size_t)wg * 8192;
    for (int i = tid; i < 8192; i += TPB) {
      float v = frames[base + i];
      unsigned short h = bf_hi(v);
      xhi[base + i] = h;
      xlo[base + i] = bf_lo(v, h);
    }
  }
  // ---- prologue: weight streams ----
  if (m == 0) {
    writeStream(Wg1, 1024, n * 32, wsb + OFF_WG1S + (size_t)n * 81920, 4, 5, 2, 18);
    writeStream(Wc1, 512, n * 16, wsb + OFF_WC1S + (size_t)n * 40960, 4, 5, 1, 18);
    writeStream(Wg2, 1024, n * 32, wsb + OFF_WG2S + (size_t)n * 131072, 4, 8, 2, 32);
    writeStream(Wc2, 512, n * 16, wsb + OFF_WC2S + (size_t)n * 65536, 4, 8, 1, 32);
  }
  if (wg < 16) writeStream(Wh, 256, wg * 16, wsb + OFF_WHS + (size_t)wg * 32768, 8, 2, 1, 16);
  if (wg < 4)  writeStream(Wp, 64, wg * 16, wsb + OFF_WPS + (size_t)wg * 16384, 8, 1, 1, 8);
  gbarN(allb, NWG);

  const char* wg1s = (const char*)(wsb + OFF_WG1S + (size_t)n * 81920);
  const char* wc1s = (const char*)(wsb + OFF_WC1S + (size_t)n * 40960);
  const char* wg2s = (const char*)(wsb + OFF_WG2S + (size_t)n * 131072);
  const char* wc2s = (const char*)(wsb + OFF_WC2S + (size_t)n * 65536);
  const int b2 = n & 15, a2 = n >> 4;            // P2b tile within group
  const int b4 = n & 3, a4 = (n >> 2) & 1;       // P4b tile (n<8 active)
  const char* whs = (const char*)(wsb + OFF_WHS + (size_t)b2 * 32768);
  const char* wps = (const char*)(wsb + OFF_WPS + (size_t)b4 * 16384);

  for (int t = 0; t <= T_; ++t) {
    const int p = t & 1, q = p ^ 1;
    unsigned short* h1hi_p = (unsigned short*)(wsb + OFF_HP + (size_t)p * 4 * HPB);
    unsigned short* h1lo_p = h1hi_p + 131072;
    unsigned short* h2hi_p = h1hi_p + 262144;
    unsigned short* h2lo_p = h1hi_p + 393216;
    unsigned short* h1hi_q = (unsigned short*)(wsb + OFF_HP + (size_t)q * 4 * HPB);
    unsigned short* h1lo_q = h1hi_q + 131072;
    unsigned short* h2hi_q = h1hi_q + 262144;
    unsigned short* h2lo_q = h1hi_q + 393216;

    // ---- P1: gates1 ----
    if (t < T_) {
      mm_phase<2, 2, 4, 18, 5, 64>(xhi, xlo, 8192, t * 64, h1hi_p, h1lo_p, 512,
                                   wg1s, red, row0);
      epi<2, 2, 4>(red, row0, n * 32, [&](int row, int col, float z) {
        z += bg1[col];
        float s = sigmoidf_(z);
        if (col < 512) {
          size_t ix = (size_t)row * 512 + col;
          float h = bf_f(h1hi_p[ix]) + bf_f(h1lo_p[ix]);
          float rh = s * h;
          unsigned short hh = bf_hi(rh);
          rh1hi[ix] = hh;
          rh1lo[ix] = bf_lo(rh, hh);
        } else {
          g1u[(size_t)row * 512 + col - 512] = s;
        }
      });
    }
    gbarN(gb, 32);

    // ---- P2: cand1 + h1 update ----
    if (t < T_) {
      mm_phase<2, 1, 4, 18, 5, 64>(xhi, xlo, 8192, t * 64, rh1hi, rh1lo, 512,
                                   wc1s, red, row0);
      epi<2, 1, 4>(red, row0, n * 16, [&](int row, int col, float z) {
        z += bc1[col];
        float c = tanhf_(z);
        size_t ix = (size_t)row * 512 + col;
        float u = g1u[ix];
        float h = bf_f(h1hi_p[ix]) + bf_f(h1lo_p[ix]);
        float hn = u * h + (1.f - u) * c;
        unsigned short hh = bf_hi(hn);
        h1hi_q[ix] = hh;
        h1lo_q[ix] = bf_lo(hn, hh);
      });
    }
    // ---- P2b: hidden = elu(h2 @ Wh + bh), pipelined 1 step behind ----
    if (t > 0) {
      int r0b = row0 + 16 * a2;
      mm_phase<1, 1, 8, 16, 2, 512>(h2hi_p, h2lo_p, 512, 0, nullptr, nullptr, 0,
                                    whs, red, r0b);
      epi<1, 1, 8>(red, r0b, 16 * b2, [&](int row, int col, float z) {
        z += bh[col];
        float ev = z > 0.f ? z : __expf(z) - 1.f;
        size_t ix = (size_t)row * 256 + col;
        unsigned short hh = bf_hi(ev);
        hidhi[ix] = hh;
        hidlo[ix] = bf_lo(ev, hh);
      });
    }
    gbarN(gb, 32);

    // ---- P3: gates2 ----
    if (t < T_) {
      mm_phase<2, 2, 4, 32, 8, 512>(h1hi_q, h1lo_q, 512, 0, h2hi_p, h2lo_p, 512,
                                    wg2s, red, row0);
      epi<2, 2, 4>(red, row0, n * 32, [&](int row, int col, float z) {
        z += bg2[col];
        float s = sigmoidf_(z);
        if (col < 512) {
          size_t ix = (size_t)row * 512 + col;
          float h = bf_f(h2hi_p[ix]) + bf_f(h2lo_p[ix]);
          float rh = s * h;
          unsigned short hh = bf_hi(rh);
          rh2hi[ix] = hh;
          rh2lo[ix] = bf_lo(rh, hh);
        } else {
          g2u[(size_t)row * 512 + col - 512] = s;
        }
      });
    }
    gbarN(gb, 32);

    // ---- P4: cand2 + h2 update ----
    if (t < T_) {
      mm_phase<2, 1, 4, 32, 8, 512>(h1hi_q, h1lo_q, 512, 0, rh2hi, rh2lo, 512,
                                    wc2s, red, row0);
      epi<2, 1, 4>(red, row0, n * 16, [&](int row, int col, float z) {
        z += bc2[col];
        float c = tanhf_(z);
        size_t ix = (size_t)row * 512 + col;
        float u = g2u[ix];
        float h = bf_f(h2hi_p[ix]) + bf_f(h2lo_p[ix]);
        float hn = u * h + (1.f - u) * c;
        unsigned short hh = bf_hi(hn);
        h2hi_q[ix] = hh;
        h2lo_q[ix] = bf_lo(hn, hh);
      });
    }
    // ---- P4b: out[:, t-1, :] = hid @ Wp + bp ----
    if (t > 0 && n < 8) {
      int r0b = row0 + 16 * a4;
      mm_phase<1, 1, 8, 8, 1, 256>(hidhi, hidlo, 256, 0, nullptr, nullptr, 0,
                                   wps, red, r0b);
      epi<1, 1, 8>(red, r0b, 16 * b4, [&](int row, int col, float z) {
        out[(size_t)row * 8192 + (size_t)(t - 1) * 64 + col] = z + bp[col];
      });
    }
  }
}

// ======================= R2 fallback (proven fp32 path) ====================
constexpr size_t F_SZ_H   = (size_t)N_ * U_;
constexpr size_t F_OFF_H1 = 0;
constexpr size_t F_OFF_H2 = F_OFF_H1 + 2 * F_SZ_H;
constexpr size_t F_OFF_BAR = F_OFF_H2 + 2 * F_SZ_H;
constexpr size_t F_OFF_G1 = F_OFF_BAR + 64;
constexpr size_t F_OFF_G2 = F_OFF_G1 + (size_t)N_ * 1024;
constexpr size_t F_OFF_HID = F_OFF_G2 + (size_t)N_ * 1024;
constexpr int LDP = 257;

template <int CK, bool GATED>
__device__ __forceinline__ void stage(float (*lds)[LDP],
                                      const float* __restrict__ src, int sStride, int sOff,
                                      const float* __restrict__ gate, int gStride, int gOff,
                                      int row0) {
  constexpr int PER = CK / 16;
  const int r = threadIdx.x >> 4;
  const int c0 = (threadIdx.x & 15) * PER;
  const float* s = src + (size_t)(row0 + r) * sStride + sOff + c0;
  float4 a0, a1, a2, a3;
  a0 = *(const float4*)(s);
  if constexpr (PER >= 8) a1 = *(const float4*)(s + 4);
  if constexpr (PER >= 16) { a2 = *(const float4*)(s + 8); a3 = *(const float4*)(s + 12); }
  if constexpr (GATED) {
    const float* g = gate + (size_t)(row0 + r) * gStride + gOff + c0;
    float4 g0 = *(const float4*)(g);
    a0.x *= g0.x; a0.y *= g0.y; a0.z *= g0.z; a0.w *= g0.w;
    if constexpr (PER >= 8) {
      float4 g1v = *(const float4*)(g + 4);
      a1.x *= g1v.x; a1.y *= g1v.y; a1.z *= g1v.z; a1.w *= g1v.w;
    }
    if constexpr (PER >= 16) {
      float4 g2v = *(const float4*)(g + 8);
      float4 g3v = *(const float4*)(g + 12);
      a2.x *= g2v.x; a2.y *= g2v.y; a2.z *= g2v.z; a2.w *= g2v.w;
      a3.x *= g3v.x; a3.y *= g3v.y; a3.z *= g3v.z; a3.w *= g3v.w;
    }
  }
  float* d = &lds[r][c0];
  d[0] = a0.x; d[1] = a0.y; d[2] = a0.z; d[3] = a0.w;
  if constexpr (PER >= 8) { d[4] = a1.x; d[5] = a1.y; d[6] = a1.z; d[7] = a1.w; }
  if constexpr (PER >= 16) {
    d[8] = a2.x; d[9] = a2.y; d[10] = a2.z; d[11] = a2.w;
    d[12] = a3.x; d[13] = a3.y; d[14] = a3.z; d[15] = a3.w;
  }
}
template <int CK>
__device__ __forceinline__ void fma2(float2& acc, const float (*lds)[LDP], int row,
                                     const float* __restrict__ B, int ldB) {
#pragma unroll 8
  for (int k = 0; k < CK; ++k) {
    const float a = lds[row][k];
    const float2 b = *(const float2*)(B + (size_t)k * ldB);
    acc.x = fmaf(a, b.x, acc.x);
    acc.y = fmaf(a, b.y, acc.y);
  }
}
template <int CK>
__device__ __forceinline__ void fma1(float& acc, const float (*lds)[LDP], int row,
                                     const float* __restrict__ B, int ldB) {
#pragma unroll 8
  for (int k = 0; k < CK; ++k) acc = fmaf(lds[row][k], B[(size_t)k * ldB], acc);
}

extern "C" __global__ __launch_bounds__(TPB, 2)
void gru_persistent(const float* __restrict__ frames,
                    const float* __restrict__ Wg1, const float* __restrict__ bg1,
                    const float* __restrict__ Wc1, const float* __restrict__ bc1,
                    const float* __restrict__ Wg2, const float* __restrict__ bg2,
                    const float* __restrict__ Wc2, const float* __restrict__ bc2,
                    const float* __restrict__ Wh,  const float* __restrict__ bh,
                    const float* __restrict__ Wp,  const float* __restrict__ bp,
                    float* __restrict__ out, float* __restrict__ ws) {
  __shared__ float lds[32][LDP];
  float* h1b = ws + F_OFF_H1;
  float* h2b = ws + F_OFF_H2;
  unsigned* bar = (unsigned*)(ws + F_OFF_BAR);
  float* g1 = ws + F_OFF_G1;
  float* g2 = ws + F_OFF_G2;
  float* hid = ws + F_OFF_HID;
  const int tid = threadIdx.x;
  const int wg = blockIdx.x;
  const int xcd = wg & 7, grp = wg >> 3;
  const int m_blk = grp >> 2, n_blk = (xcd << 2) | (grp & 3);
  const int row0 = m_blk * 32;
  const int rowA = tid & 31, cq = tid >> 5;
  const int nrow = row0 + rowA;
  for (int t = 0; t <= T_; ++t) {
    const int p = t & 1;
    const float* h1o = h1b + (size_t)p * F_SZ_H;
    float* h1n = h1b + (size_t)(p ^ 1) * F_SZ_H;
    const float* h2o = h2b + (size_t)p * F_SZ_H;
    float* h2n = h2b + (size_t)(p ^ 1) * F_SZ_H;
    if (t < T_) {
      float2 acc = {0.f, 0.f};
      const int col = n_blk * 32 + cq * 2;
      stage<64, false>(lds, frames, T_ * C_, t * C_, nullptr, 0, 0, row0);
      __syncthreads();
      fma2<64>(acc, lds, rowA, Wg1 + col, 1024);
      __syncthreads();
#pragma unroll 1
      for (int ch = 0; ch < 2; ++ch) {
        stage<256, false>(lds, h1o, U_, ch * 256, nullptr, 0, 0, row0);
        __syncthreads();
        fma2<256>(acc, lds, rowA, Wg1 + (size_t)(64 + ch * 256) * 1024 + col, 1024);
        __syncthreads();
      }
      const float2 bb = *(const float2*)(bg1 + col);
      float* gp = g1 + (size_t)nrow * 1024 + col;
      gp[0] = sigmoidf_(acc.x + bb.x);
      gp[1] = sigmoidf_(acc.y + bb.y);
    }
    gbarN(bar, NWG);
    if (t < T_) {
      float acc = 0.f;
      const int col = n_blk * 16 + cq;
      stage<64, false>(lds, frames, T_ * C_, t * C_, nullptr, 0, 0, row0);
      __syncthreads();
      fma1<64>(acc, lds, rowA, Wc1 + col, U_);
      __syncthreads();
#pragma unroll 1
      for (int ch = 0; ch < 2; ++ch) {
        stage<256, true>(lds, h1o, U_, ch * 256, g1, 1024, ch * 256, row0);
        __syncthreads();
        fma1<256>(acc, lds, rowA, Wc1 + (size_t)(64 + ch * 256) * U_ + col, U_);
        __syncthreads();
      }
      const float cv = tanhf_(acc + bc1[col]);
      const float u = g1[(size_t)nrow * 1024 + 512 + col];
      const float ho = h1o[(size_t)nrow * U_ + col];
      h1n[(size_t)nrow * U_ + col] = u * ho + (1.f - u) * cv;
    }
    if (t > 0) {
      float acc = 0.f;
      const int col = n_blk * 8 + (cq & 7);
      const bool act = tid < 256;
#pragma unroll 1
      for (int ch = 0; ch < 2; ++ch) {
        stage<256, false>(lds, h2o, U_, ch * 256, nullptr, 0, 0, row0);
        __syncthreads();
        if (act) fma1<256>(acc, lds, rowA, Wh + (size_t)(ch * 256) * H_ + col, H_);
        __syncthreads();
      }
      if (act) {
        const float z = acc + bh[col];
        hid[(size_t)nrow * H_ + col] = z > 0.f ? z : __expf(z) - 1.f;
      }
    }
    gbarN(bar, NWG);
    if (t < T_) {
      float2 acc = {0.f, 0.f};
      const int col = n_blk * 32 + cq * 2;
#pragma unroll 1
      for (int ch = 0; ch < 4; ++ch) {
        const float* src = (ch < 2) ? h1n : h2o;
        stage<256, false>(lds, src, U_, (ch & 1) * 256, nullptr, 0, 0, row0);
        __syncthreads();
        fma2<256>(acc, lds, rowA, Wg2 + (size_t)(ch * 256) * 1024 + col, 1024);
        __syncthreads();
      }
      const float2 bb = *(const float2*)(bg2 + col);
      float* gp = g2 + (size_t)nrow * 1024 + col;
      gp[0] = sigmoidf_(acc.x + bb.x);
      gp[1] = sigmoidf_(acc.y + bb.y);
    }
    gbarN(bar, NWG);
    if (t < T_) {
      float acc = 0.f;
      const int col = n_blk * 16 + cq;
#pragma unroll 1
      for (int ch = 0; ch < 4; ++ch) {
        if (ch < 2) stage<256, false>(lds, h1n, U_, (ch & 1) * 256, nullptr, 0, 0, row0);
        else stage<256, true>(lds, h2o, U_, (ch & 1) * 256, g2, 1024, (ch & 1) * 256, row0);
        __syncthreads();
        fma1<256>(acc, lds, rowA, Wc2 + (size_t)(ch * 256) * U_ + col, U_);
        __syncthreads();
      }
      const float cv = tanhf_(acc + bc2[col]);
      const float u = g2[(size_t)nrow * 1024 + 512 + col];
      const float ho = h2o[(size_t)nrow * U_ + col];
      h2n[(size_t)nrow * U_ + col] = u * ho + (1.f - u) * cv;
    }
    if (t > 0) {
      if (tid < 64) {
        float acc = 0.f;
        const int col = n_blk * 2 + cq;
        const float* hrow = hid + (size_t)nrow * H_;
#pragma unroll 8
        for (int k = 0; k < H_; ++k) acc = fmaf(hrow[k], Wp[(size_t)k * C_ + col], acc);
        out[(size_t)nrow * (T_ * C_) + (size_t)(t - 1) * C_ + col] = acc + bp[col];
      }
    }
  }
}

// ---------------- launch ---------------------------------------------------
extern "C" void kernel_launch(void* const* d_in, const int* in_sizes, int n_in,
                              void* d_out, int out_size, void* d_ws, size_t ws_size,
                              hipStream_t stream) {
  const float* frames = (const float*)d_in[0];
  const float* Wg1 = (const float*)d_in[1];
  const float* bg1 = (const float*)d_in[2];
  const float* Wc1 = (const float*)d_in[3];
  const float* bc1 = (const float*)d_in[4];
  const float* Wg2 = (const float*)d_in[5];
  const float* bg2 = (const float*)d_in[6];
  const float* Wc2 = (const float*)d_in[7];
  const float* bc2 = (const float*)d_in[8];
  const float* Wh = (const float*)d_in[9];
  const float* bh = (const float*)d_in[10];
  const float* Wp = (const float*)d_in[11];
  const float* bp = (const float*)d_in[12];
  float* out = (float*)d_out;

  if (ws_size >= WS_NEED) {
    char* wsb = (char*)d_ws;
    // zero barrier area + h-plane buffer 0 (h1hi0,h1lo0,h2hi0,h2lo0)
    hipMemsetAsync(d_ws, 0, 2048 + 4 * HPB, stream);
    void* args[] = {(void*)&frames, (void*)&Wg1, (void*)&bg1, (void*)&Wc1, (void*)&bc1,
                    (void*)&Wg2, (void*)&bg2, (void*)&Wc2, (void*)&bc2,
                    (void*)&Wh, (void*)&bh, (void*)&Wp, (void*)&bp,
                    (void*)&out, (void*)&wsb};
    hipError_t err = hipLaunchCooperativeKernel((const void*)gru_mfma,
                                                dim3(NWG), dim3(TPB), args, 0, stream);
    if (err != hipSuccess) {
      (void)hipGetLastError();
      hipLaunchKernelGGL(gru_mfma, dim3(NWG), dim3(TPB), 0, stream,
                         frames, Wg1, bg1, Wc1, bc1, Wg2, bg2, Wc2, bc2,
                         Wh, bh, Wp, bp, out, wsb);
    }
  } else {
    float* ws = (float*)d_ws;
    hipMemsetAsync(d_ws, 0, F_OFF_G1 * sizeof(float), stream);
    void* args[] = {(void*)&frames, (void*)&Wg1, (void*)&bg1, (void*)&Wc1, (void*)&bc1,
                    (void*)&Wg2, (void*)&bg2, (void*)&Wc2, (void*)&bc2,
                    (void*)&Wh, (void*)&bh, (void*)&Wp, (void*)&bp,
                    (void*)&out, (void*)&ws};
    hipError_t err = hipLaunchCooperativeKernel((const void*)gru_persistent,
                                                dim3(NWG), dim3(TPB), args, 0, stream);
    if (err != hipSuccess) {
      (void)hipGetLastError();
      hipLaunchKernelGGL(gru_persistent, dim3(NWG), dim3(TPB), 0, stream,
                         frames, Wg1, bg1, Wc1, bc1, Wg2, bg2, Wc2, bc2,
                         Wh, bh, Wp, bp, out, ws);
    }
  }
}

// Round 4
// 5528.157 us; speedup vs baseline: 6.1084x; 2.3169x over previous
//
#include <hip/hip_runtime.h>
#include <cstdint>
#include <cstddef>

// ---------------------------------------------------------------------------
// VWFutureModel: 2-layer GRU scan (T=128, N=256, C=64, U=512) + dense head.
// R4: fence-free coherence protocol.
//  - exchanged per-step data (h planes, rh, u-gates, hid) accessed via
//    RELAXED AGENT-scope atomic loads/stores (L2-bypassing, pipelined)
//  - steady-state group barriers have NO threadfence -> local L2 never
//    invalidated -> pre-swizzled weight streams stay L2-resident
//  - ordering at barrier: s_waitcnt vmcnt(0) (all waves) + relaxed arrive
//  - epilogues emit column-pairs, stores packed u32/u64
//  - prologue keeps one fully-fenced grid barrier (x planes + weights)
// ---------------------------------------------------------------------------

#define NWG 256
#define TPB 512

constexpr int N_ = 256, T_ = 128, C_ = 64, U_ = 512, H_ = 256;

typedef __attribute__((ext_vector_type(8))) short short8;
typedef __attribute__((ext_vector_type(4))) float f32x4;

// ---------------- byte offsets in workspace (MFMA kernel) ------------------
constexpr size_t HPB      = 262144;                 // one h plane: 256*512*2B
constexpr size_t OFF_BAR  = 0;                      // 2048 B barrier area
constexpr size_t OFF_HP   = 2048;                   // 2 bufs x [h1hi,h1lo,h2hi,h2lo]
constexpr size_t OFF_RH1  = OFF_HP + 8 * HPB;
constexpr size_t OFF_RH2  = OFF_RH1 + 524288;
constexpr size_t OFF_G1U  = OFF_RH2 + 524288;       // fp32 [256][512]
constexpr size_t OFF_G2U  = OFF_G1U + 524288;
constexpr size_t OFF_HID  = OFF_G2U + 524288;       // hid hi,lo (2*131072)
constexpr size_t OFF_XHI  = OFF_HID + 262144;       // [256][8192] bf16
constexpr size_t OFF_XLO  = OFF_XHI + 4194304;
constexpr size_t OFF_WG1S = OFF_XLO + 4194304;      // 32 * 81920
constexpr size_t OFF_WC1S = OFF_WG1S + 32 * 81920;  // 32 * 40960
constexpr size_t OFF_WG2S = OFF_WC1S + 32 * 40960;  // 32 * 131072
constexpr size_t OFF_WC2S = OFF_WG2S + 32 * 131072; // 32 * 65536
constexpr size_t OFF_WHS  = OFF_WC2S + 32 * 65536;  // 16 * 32768
constexpr size_t OFF_WPS  = OFF_WHS + 16 * 32768;   // 4 * 16384
constexpr size_t WS_NEED  = OFF_WPS + 4 * 16384;    // ~23.7 MB

// ---------------- scalar helpers -------------------------------------------
__device__ __forceinline__ float sigmoidf_(float z) {
  return 1.0f / (1.0f + __expf(-z));
}
__device__ __forceinline__ float tanhf_(float z) {
  return 1.0f - 2.0f / (1.0f + __expf(2.0f * z));
}
__device__ __forceinline__ unsigned short bf_hi(float f) {
  unsigned int x = __float_as_uint(f);
  unsigned int r = x + 0x7FFFu + ((x >> 16) & 1u);
  return (unsigned short)(r >> 16);
}
__device__ __forceinline__ float bf_f(unsigned short h) {
  return __uint_as_float(((unsigned int)h) << 16);
}
__device__ __forceinline__ unsigned short bf_lo(float f, unsigned short hi) {
  return bf_hi(f - bf_f(hi));
}

// ---------------- coherent access helpers (agent scope, relaxed) -----------
__device__ __forceinline__ unsigned lda32(const unsigned short* p) {
  return __hip_atomic_load((const unsigned*)p, __ATOMIC_RELAXED, __HIP_MEMORY_SCOPE_AGENT);
}
__device__ __forceinline__ void sta32(unsigned short* p, unsigned v) {
  __hip_atomic_store((unsigned*)p, v, __ATOMIC_RELAXED, __HIP_MEMORY_SCOPE_AGENT);
}
__device__ __forceinline__ unsigned long long lda64f(const float* p) {
  return __hip_atomic_load((const unsigned long long*)p, __ATOMIC_RELAXED, __HIP_MEMORY_SCOPE_AGENT);
}
__device__ __forceinline__ void sta64f(float* p, float a, float b) {
  union { float f[2]; unsigned long long q; } x;
  x.f[0] = a; x.f[1] = b;
  __hip_atomic_store((unsigned long long*)p, x.q, __ATOMIC_RELAXED, __HIP_MEMORY_SCOPE_AGENT);
}

template <bool S>
__device__ __forceinline__ short8 ld8c(const unsigned short* p) {
  if constexpr (S) {
    union { unsigned long long q[2]; short8 s; } x;
    x.q[0] = __hip_atomic_load((const unsigned long long*)p, __ATOMIC_RELAXED, __HIP_MEMORY_SCOPE_AGENT);
    x.q[1] = __hip_atomic_load((const unsigned long long*)p + 1, __ATOMIC_RELAXED, __HIP_MEMORY_SCOPE_AGENT);
    return x.s;
  } else {
    union { uint4 u; short8 s; } x;
    x.u = *(const uint4*)p;
    return x.s;
  }
}

// ---------------- barriers -------------------------------------------------
// Fence-free group barrier: all waves drain vmcnt (coherent stores reach the
// coherence point), then one relaxed agent-scope arrive + epoch poll.
__device__ __forceinline__ void gbarN(unsigned* b, unsigned np) {
  asm volatile("s_waitcnt vmcnt(0) lgkmcnt(0)" ::: "memory");
  __syncthreads();
  if (threadIdx.x == 0) {
    unsigned e = __hip_atomic_load(b + 16, __ATOMIC_RELAXED, __HIP_MEMORY_SCOPE_AGENT);
    unsigned a = __hip_atomic_fetch_add(b, 1u, __ATOMIC_RELAXED, __HIP_MEMORY_SCOPE_AGENT);
    if (a == np - 1) {
      __hip_atomic_store(b, 0u, __ATOMIC_RELAXED, __HIP_MEMORY_SCOPE_AGENT);
      __hip_atomic_store(b + 16, e + 1u, __ATOMIC_RELAXED, __HIP_MEMORY_SCOPE_AGENT);
    } else {
      unsigned spins = 0;
      while (__hip_atomic_load(b + 16, __ATOMIC_RELAXED, __HIP_MEMORY_SCOPE_AGENT) == e) {
        __builtin_amdgcn_s_sleep(1);
        if (++spins > (1u << 20)) break;  // escape hatch: fail, don't hang
      }
    }
  }
  __syncthreads();
}

// Fully-fenced barrier (prologue + fallback kernel): makes normal cached
// stores visible device-wide (release writeback / acquire invalidate).
__device__ __forceinline__ void gbarF(unsigned* b, unsigned np) {
  __syncthreads();
  if (threadIdx.x == 0) {
    __threadfence();
    unsigned e = __hip_atomic_load(b + 16, __ATOMIC_RELAXED, __HIP_MEMORY_SCOPE_AGENT);
    unsigned a = __hip_atomic_fetch_add(b, 1u, __ATOMIC_ACQ_REL, __HIP_MEMORY_SCOPE_AGENT);
    if (a == np - 1) {
      __hip_atomic_store(b, 0u, __ATOMIC_RELAXED, __HIP_MEMORY_SCOPE_AGENT);
      __hip_atomic_store(b + 16, e + 1u, __ATOMIC_RELEASE, __HIP_MEMORY_SCOPE_AGENT);
    } else {
      unsigned spins = 0;
      while (__hip_atomic_load(b + 16, __ATOMIC_RELAXED, __HIP_MEMORY_SCOPE_AGENT) == e) {
        __builtin_amdgcn_s_sleep(1);
        if (++spins > (1u << 20)) break;
      }
    }
    __threadfence();
  }
  __syncthreads();
}

// ---------------- weight stream swizzle (prologue) -------------------------
__device__ void writeStream(const float* __restrict__ W, int ldW, int colbase,
                            char* sb, int nsplit, int slots, int tnn, int nch) {
  const int tid = threadIdx.x;
  const int lane = tid & 63;
  const int e = tid >> 6;  // 0..7
  const int nf = nsplit * slots * tnn;
  for (int f = 0; f < nf; ++f) {
    int tn = f % tnn;
    int ci = (f / tnn) % slots;
    int ks = f / (tnn * slots);
    int c = ks + ci * nsplit;
    if (c >= nch) continue;
    int k = 32 * c + ((lane >> 4) << 3) + e;
    int col = colbase + 16 * tn + (lane & 15);
    float v = W[(size_t)k * ldW + col];
    unsigned short hi = bf_hi(v);
    unsigned short lo = bf_lo(v, hi);
    unsigned short* fb = (unsigned short*)(sb + (size_t)f * 2048);
    fb[lane * 8 + e] = hi;
    fb[512 + lane * 8 + e] = lo;
  }
}

// ---------------- MFMA phase -----------------------------------------------
// S1/S2: whether A1/A2 need coherent (agent) loads.
template <int TM, int TN, int NSPLIT, int NCH, int SLOTS, int KA, bool S1, bool S2>
__device__ __forceinline__ void mm_phase(
    const unsigned short* __restrict__ A1h, const unsigned short* __restrict__ A1l,
    int lda1, int aoff,
    const unsigned short* __restrict__ A2h, const unsigned short* __restrict__ A2l,
    int lda2, const char* __restrict__ bstr, float* red, int row0loc) {
  const int tid = threadIdx.x;
  const int ww = tid >> 6, lane = tid & 63;
  const int tm = ww / NSPLIT;
  const int ks = ww % NSPLIT;
  __syncthreads();  // protect red reuse from previous phase reads
  f32x4 acc0[TN], acc1[TN], acc2[TN];
#pragma unroll
  for (int tn = 0; tn < TN; ++tn) {
    acc0[tn] = (f32x4){0.f, 0.f, 0.f, 0.f};
    acc1[tn] = (f32x4){0.f, 0.f, 0.f, 0.f};
    acc2[tn] = (f32x4){0.f, 0.f, 0.f, 0.f};
  }
  const int arow = row0loc + 16 * tm + (lane & 15);
  const int kgrp = (lane >> 4) << 3;
#pragma unroll 2
  for (int ci = 0; ci < SLOTS; ++ci) {
    int c = ks + ci * NSPLIT;
    if (c >= NCH) break;
    int ak = 32 * c + kgrp;
    short8 Ah, Al;
    if (ak < KA) {
      Ah = ld8c<S1>(A1h + (size_t)arow * lda1 + aoff + ak);
      Al = ld8c<S1>(A1l + (size_t)arow * lda1 + aoff + ak);
    } else {
      int ak2 = ak - KA;
      Ah = ld8c<S2>(A2h + (size_t)arow * lda2 + ak2);
      Al = ld8c<S2>(A2l + (size_t)arow * lda2 + ak2);
    }
    const char* fb = bstr + ((size_t)(ks * SLOTS + ci) * TN) * 2048;
#pragma unroll
    for (int tn = 0; tn < TN; ++tn) {
      short8 Bh = ld8c<false>((const unsigned short*)(fb + (size_t)tn * 2048) + lane * 8);
      short8 Bl = ld8c<false>((const unsigned short*)(fb + (size_t)tn * 2048 + 1024) + lane * 8);
      acc0[tn] = __builtin_amdgcn_mfma_f32_16x16x32_bf16(Ah, Bh, acc0[tn], 0, 0, 0);
      acc1[tn] = __builtin_amdgcn_mfma_f32_16x16x32_bf16(Ah, Bl, acc1[tn], 0, 0, 0);
      acc2[tn] = __builtin_amdgcn_mfma_f32_16x16x32_bf16(Al, Bh, acc2[tn], 0, 0, 0);
    }
  }
#pragma unroll
  for (int tn = 0; tn < TN; ++tn) {
    f32x4 s = acc0[tn] + acc1[tn] + acc2[tn];
    int slot = (tm * TN + tn) * NSPLIT + ks;
    *(f32x4*)(&red[slot * 256 + lane * 4]) = s;
  }
  __syncthreads();
}

// reduce partials + run epilogue per COLUMN-PAIR (col, col+1)
template <int TM, int TN, int NSPLIT, typename F>
__device__ __forceinline__ void epi2(const float* red, int row0loc, int col0, F f) {
  for (int idx = threadIdx.x; idx < TM * TN * 128; idx += TPB) {
    int tg = idx >> 7;
    int r  = (idx >> 3) & 15;
    int cp = idx & 7;
    int e0 = (((((r >> 2) << 4) | (cp << 1)) << 2) | (r & 3));
    float z0 = 0.f, z1 = 0.f;
#pragma unroll
    for (int s = 0; s < NSPLIT; ++s) {
      const float* rp = red + (tg * NSPLIT + s) * 256;
      z0 += rp[e0];
      z1 += rp[e0 + 4];
    }
    int tm = tg / TN, tn = tg % TN;
    f(row0loc + 16 * tm + r, col0 + 16 * tn + cp * 2, z0, z1);
  }
}

// ---------------- MFMA kernel ----------------------------------------------
extern "C" __global__ __launch_bounds__(TPB, 2)
void gru_mfma(const float* __restrict__ frames,
              const float* __restrict__ Wg1, const float* __restrict__ bg1,
              const float* __restrict__ Wc1, const float* __restrict__ bc1,
              const float* __restrict__ Wg2, const float* __restrict__ bg2,
              const float* __restrict__ Wc2, const float* __restrict__ bc2,
              const float* __restrict__ Wh,  const float* __restrict__ bh,
              const float* __restrict__ Wp,  const float* __restrict__ bp,
              float* __restrict__ out, char* __restrict__ wsb) {
  __shared__ float red[4096];  // 16 KB

  const int tid = threadIdx.x;
  const int wg = blockIdx.x;
  const int xcd = wg & 7;
  const int grp = wg >> 3;
  const int m = grp >> 2;                 // 0..7  row group (rows 32m..32m+31)
  const int n = (xcd << 2) | (grp & 3);   // 0..31 col slice (XCD-local weights)
  const int row0 = m * 32;

  unsigned* barw = (unsigned*)(wsb + OFF_BAR);
  unsigned* gb = barw + m * 32;    // per-group barrier
  unsigned* allb = barw + 256;     // global barrier (prologue only)

  unsigned short* xhi = (unsigned short*)(wsb + OFF_XHI);
  unsigned short* xlo = (unsigned short*)(wsb + OFF_XLO);
  unsigned short* rh1hi = (unsigned short*)(wsb + OFF_RH1);
  unsigned short* rh1lo = (unsigned short*)(wsb + OFF_RH1 + 262144);
  unsigned short* rh2hi = (unsigned short*)(wsb + OFF_RH2);
  unsigned short* rh2lo = (unsigned short*)(wsb + OFF_RH2 + 262144);
  float* g1u = (float*)(wsb + OFF_G1U);
  float* g2u = (float*)(wsb + OFF_G2U);
  unsigned short* hidhi = (unsigned short*)(wsb + OFF_HID);
  unsigned short* hidlo = (unsigned short*)(wsb + OFF_HID + 131072);

  // ---- prologue: x planes (normal stores; fenced barrier below) ----
  {
    const size_t base = (size_t)wg * 8192;
    for (int i = tid; i < 8192; i += TPB) {
      float v = frames[base + i];
      unsigned short h = bf_hi(v);
      xhi[base + i] = h;
      xlo[base + i] = bf_lo(v, h);
    }
  }
  // ---- prologue: weight streams ----
  if (m == 0) {
    writeStream(Wg1, 1024, n * 32, wsb + OFF_WG1S + (size_t)n * 81920, 4, 5, 2, 18);
    writeStream(Wc1, 512, n * 16, wsb + OFF_WC1S + (size_t)n * 40960, 4, 5, 1, 18);
    writeStream(Wg2, 1024, n * 32, wsb + OFF_WG2S + (size_t)n * 131072, 4, 8, 2, 32);
    writeStream(Wc2, 512, n * 16, wsb + OFF_WC2S + (size_t)n * 65536, 4, 8, 1, 32);
  }
  if (wg < 16) writeStream(Wh, 256, wg * 16, wsb + OFF_WHS + (size_t)wg * 32768, 8, 2, 1, 16);
  if (wg < 4)  writeStream(Wp, 64, wg * 16, wsb + OFF_WPS + (size_t)wg * 16384, 8, 1, 1, 8);
  gbarF(allb, NWG);  // fenced: publish x + weights device-wide, once

  const char* wg1s = (const char*)(wsb + OFF_WG1S + (size_t)n * 81920);
  const char* wc1s = (const char*)(wsb + OFF_WC1S + (size_t)n * 40960);
  const char* wg2s = (const char*)(wsb + OFF_WG2S + (size_t)n * 131072);
  const char* wc2s = (const char*)(wsb + OFF_WC2S + (size_t)n * 65536);
  const int b2 = n & 15, a2 = n >> 4;            // P2b tile within group
  const int b4 = n & 3, a4 = (n >> 2) & 1;       // P4b tile (n<8 active)
  const char* whs = (const char*)(wsb + OFF_WHS + (size_t)b2 * 32768);
  const char* wps = (const char*)(wsb + OFF_WPS + (size_t)b4 * 16384);

  for (int t = 0; t <= T_; ++t) {
    const int p = t & 1, q = p ^ 1;
    unsigned short* h1hi_p = (unsigned short*)(wsb + OFF_HP + (size_t)p * 4 * HPB);
    unsigned short* h1lo_p = h1hi_p + 131072;
    unsigned short* h2hi_p = h1hi_p + 262144;
    unsigned short* h2lo_p = h1hi_p + 393216;
    unsigned short* h1hi_q = (unsigned short*)(wsb + OFF_HP + (size_t)q * 4 * HPB);
    unsigned short* h1lo_q = h1hi_q + 131072;
    unsigned short* h2hi_q = h1hi_q + 262144;
    unsigned short* h2lo_q = h1hi_q + 393216;

    // ---- P1: gates1 ----
    if (t < T_) {
      mm_phase<2, 2, 4, 18, 5, 64, false, true>(xhi, xlo, 8192, t * 64,
                                                h1hi_p, h1lo_p, 512, wg1s, red, row0);
      epi2<2, 2, 4>(red, row0, n * 32, [&](int row, int col, float z0, float z1) {
        z0 += bg1[col]; z1 += bg1[col + 1];
        float s0 = sigmoidf_(z0), s1 = sigmoidf_(z1);
        if (col < 512) {
          size_t ix = (size_t)row * 512 + col;
          unsigned hw = lda32(h1hi_p + ix), lw = lda32(h1lo_p + ix);
          float h0 = bf_f((unsigned short)hw) + bf_f((unsigned short)lw);
          float h1v = bf_f((unsigned short)(hw >> 16)) + bf_f((unsigned short)(lw >> 16));
          float r0 = s0 * h0, r1 = s1 * h1v;
          unsigned short a0 = bf_hi(r0), a1 = bf_hi(r1);
          sta32(rh1hi + ix, (unsigned)a0 | ((unsigned)a1 << 16));
          sta32(rh1lo + ix, (unsigned)bf_lo(r0, a0) | ((unsigned)bf_lo(r1, a1) << 16));
        } else {
          sta64f(g1u + (size_t)row * 512 + (col - 512), s0, s1);
        }
      });
    }
    gbarN(gb, 32);

    // ---- P2: cand1 + h1 update ----
    if (t < T_) {
      mm_phase<2, 1, 4, 18, 5, 64, false, true>(xhi, xlo, 8192, t * 64,
                                                rh1hi, rh1lo, 512, wc1s, red, row0);
      epi2<2, 1, 4>(red, row0, n * 16, [&](int row, int col, float z0, float z1) {
        z0 += bc1[col]; z1 += bc1[col + 1];
        float c0 = tanhf_(z0), c1 = tanhf_(z1);
        size_t ix = (size_t)row * 512 + col;
        unsigned long long ug = lda64f(g1u + ix);
        float u0 = __uint_as_float((unsigned)ug);
        float u1 = __uint_as_float((unsigned)(ug >> 32));
        unsigned hw = lda32(h1hi_p + ix), lw = lda32(h1lo_p + ix);
        float h0 = bf_f((unsigned short)hw) + bf_f((unsigned short)lw);
        float h1v = bf_f((unsigned short)(hw >> 16)) + bf_f((unsigned short)(lw >> 16));
        float n0 = u0 * h0 + (1.f - u0) * c0;
        float n1 = u1 * h1v + (1.f - u1) * c1;
        unsigned short a0 = bf_hi(n0), a1 = bf_hi(n1);
        sta32(h1hi_q + ix, (unsigned)a0 | ((unsigned)a1 << 16));
        sta32(h1lo_q + ix, (unsigned)bf_lo(n0, a0) | ((unsigned)bf_lo(n1, a1) << 16));
      });
    }
    // ---- P2b: hidden = elu(h2 @ Wh + bh), pipelined 1 step behind ----
    if (t > 0) {
      int r0b = row0 + 16 * a2;
      mm_phase<1, 1, 8, 16, 2, 512, true, false>(h2hi_p, h2lo_p, 512, 0,
                                                 nullptr, nullptr, 0, whs, red, r0b);
      epi2<1, 1, 8>(red, r0b, 16 * b2, [&](int row, int col, float z0, float z1) {
        z0 += bh[col]; z1 += bh[col + 1];
        float e0v = z0 > 0.f ? z0 : __expf(z0) - 1.f;
        float e1v = z1 > 0.f ? z1 : __expf(z1) - 1.f;
        size_t ix = (size_t)row * 256 + col;
        unsigned short a0 = bf_hi(e0v), a1 = bf_hi(e1v);
        sta32(hidhi + ix, (unsigned)a0 | ((unsigned)a1 << 16));
        sta32(hidlo + ix, (unsigned)bf_lo(e0v, a0) | ((unsigned)bf_lo(e1v, a1) << 16));
      });
    }
    gbarN(gb, 32);

    // ---- P3: gates2 ----
    if (t < T_) {
      mm_phase<2, 2, 4, 32, 8, 512, true, true>(h1hi_q, h1lo_q, 512, 0,
                                                h2hi_p, h2lo_p, 512, wg2s, red, row0);
      epi2<2, 2, 4>(red, row0, n * 32, [&](int row, int col, float z0, float z1) {
        z0 += bg2[col]; z1 += bg2[col + 1];
        float s0 = sigmoidf_(z0), s1 = sigmoidf_(z1);
        if (col < 512) {
          size_t ix = (size_t)row * 512 + col;
          unsigned hw = lda32(h2hi_p + ix), lw = lda32(h2lo_p + ix);
          float h0 = bf_f((unsigned short)hw) + bf_f((unsigned short)lw);
          float h1v = bf_f((unsigned short)(hw >> 16)) + bf_f((unsigned short)(lw >> 16));
          float r0 = s0 * h0, r1 = s1 * h1v;
          unsigned short a0 = bf_hi(r0), a1 = bf_hi(r1);
          sta32(rh2hi + ix, (unsigned)a0 | ((unsigned)a1 << 16));
          sta32(rh2lo + ix, (unsigned)bf_lo(r0, a0) | ((unsigned)bf_lo(r1, a1) << 16));
        } else {
          sta64f(g2u + (size_t)row * 512 + (col - 512), s0, s1);
        }
      });
    }
    gbarN(gb, 32);

    // ---- P4: cand2 + h2 update ----
    if (t < T_) {
      mm_phase<2, 1, 4, 32, 8, 512, true, true>(h1hi_q, h1lo_q, 512, 0,
                                                rh2hi, rh2lo, 512, wc2s, red, row0);
      epi2<2, 1, 4>(red, row0, n * 16, [&](int row, int col, float z0, float z1) {
        z0 += bc2[col]; z1 += bc2[col + 1];
        float c0 = tanhf_(z0), c1 = tanhf_(z1);
        size_t ix = (size_t)row * 512 + col;
        unsigned long long ug = lda64f(g2u + ix);
        float u0 = __uint_as_float((unsigned)ug);
        float u1 = __uint_as_float((unsigned)(ug >> 32));
        unsigned hw = lda32(h2hi_p + ix), lw = lda32(h2lo_p + ix);
        float h0 = bf_f((unsigned short)hw) + bf_f((unsigned short)lw);
        float h1v = bf_f((unsigned short)(hw >> 16)) + bf_f((unsigned short)(lw >> 16));
        float n0 = u0 * h0 + (1.f - u0) * c0;
        float n1 = u1 * h1v + (1.f - u1) * c1;
        unsigned short a0 = bf_hi(n0), a1 = bf_hi(n1);
        sta32(h2hi_q + ix, (unsigned)a0 | ((unsigned)a1 << 16));
        sta32(h2lo_q + ix, (unsigned)bf_lo(n0, a0) | ((unsigned)bf_lo(n1, a1) << 16));
      });
    }
    // ---- P4b: out[:, t-1, :] = hid @ Wp + bp ----
    if (t > 0 && n < 8) {
      int r0b = row0 + 16 * a4;
      mm_phase<1, 1, 8, 8, 1, 256, true, false>(hidhi, hidlo, 256, 0,
                                                nullptr, nullptr, 0, wps, red, r0b);
      epi2<1, 1, 8>(red, r0b, 16 * b4, [&](int row, int col, float z0, float z1) {
        float2 v = {z0 + bp[col], z1 + bp[col + 1]};
        *(float2*)(out + (size_t)row * 8192 + (size_t)(t - 1) * 64 + col) = v;
      });
    }
  }
}

// ======================= R2 fallback (proven fp32 path) ====================
constexpr size_t F_SZ_H   = (size_t)N_ * U_;
constexpr size_t F_OFF_H1 = 0;
constexpr size_t F_OFF_H2 = F_OFF_H1 + 2 * F_SZ_H;
constexpr size_t F_OFF_BAR = F_OFF_H2 + 2 * F_SZ_H;
constexpr size_t F_OFF_G1 = F_OFF_BAR + 64;
constexpr size_t F_OFF_G2 = F_OFF_G1 + (size_t)N_ * 1024;
constexpr size_t F_OFF_HID = F_OFF_G2 + (size_t)N_ * 1024;
constexpr int LDP = 257;

template <int CK, bool GATED>
__device__ __forceinline__ void stage(float (*lds)[LDP],
                                      const float* __restrict__ src, int sStride, int sOff,
                                      const float* __restrict__ gate, int gStride, int gOff,
                                      int row0) {
  constexpr int PER = CK / 16;
  const int r = threadIdx.x >> 4;
  const int c0 = (threadIdx.x & 15) * PER;
  const float* s = src + (size_t)(row0 + r) * sStride + sOff + c0;
  float4 a0, a1, a2, a3;
  a0 = *(const float4*)(s);
  if constexpr (PER >= 8) a1 = *(const float4*)(s + 4);
  if constexpr (PER >= 16) { a2 = *(const float4*)(s + 8); a3 = *(const float4*)(s + 12); }
  if constexpr (GATED) {
    const float* g = gate + (size_t)(row0 + r) * gStride + gOff + c0;
    float4 g0 = *(const float4*)(g);
    a0.x *= g0.x; a0.y *= g0.y; a0.z *= g0.z; a0.w *= g0.w;
    if constexpr (PER >= 8) {
      float4 g1v = *(const float4*)(g + 4);
      a1.x *= g1v.x; a1.y *= g1v.y; a1.z *= g1v.z; a1.w *= g1v.w;
    }
    if constexpr (PER >= 16) {
      float4 g2v = *(const float4*)(g + 8);
      float4 g3v = *(const float4*)(g + 12);
      a2.x *= g2v.x; a2.y *= g2v.y; a2.z *= g2v.z; a2.w *= g2v.w;
      a3.x *= g3v.x; a3.y *= g3v.y; a3.z *= g3v.z; a3.w *= g3v.w;
    }
  }
  float* d = &lds[r][c0];
  d[0] = a0.x; d[1] = a0.y; d[2] = a0.z; d[3] = a0.w;
  if constexpr (PER >= 8) { d[4] = a1.x; d[5] = a1.y; d[6] = a1.z; d[7] = a1.w; }
  if constexpr (PER >= 16) {
    d[8] = a2.x; d[9] = a2.y; d[10] = a2.z; d[11] = a2.w;
    d[12] = a3.x; d[13] = a3.y; d[14] = a3.z; d[15] = a3.w;
  }
}
template <int CK>
__device__ __forceinline__ void fma2(float2& acc, const float (*lds)[LDP], int row,
                                     const float* __restrict__ B, int ldB) {
#pragma unroll 8
  for (int k = 0; k < CK; ++k) {
    const float a = lds[row][k];
    const float2 b = *(const float2*)(B + (size_t)k * ldB);
    acc.x = fmaf(a, b.x, acc.x);
    acc.y = fmaf(a, b.y, acc.y);
  }
}
template <int CK>
__device__ __forceinline__ void fma1(float& acc, const float (*lds)[LDP], int row,
                                     const float* __restrict__ B, int ldB) {
#pragma unroll 8
  for (int k = 0; k < CK; ++k) acc = fmaf(lds[row][k], B[(size_t)k * ldB], acc);
}

extern "C" __global__ __launch_bounds__(TPB, 2)
void gru_persistent(const float* __restrict__ frames,
                    const float* __restrict__ Wg1, const float* __restrict__ bg1,
                    const float* __restrict__ Wc1, const float* __restrict__ bc1,
                    const float* __restrict__ Wg2, const float* __restrict__ bg2,
                    const float* __restrict__ Wc2, const float* __restrict__ bc2,
                    const float* __restrict__ Wh,  const float* __restrict__ bh,
                    const float* __restrict__ Wp,  const float* __restrict__ bp,
                    float* __restrict__ out, float* __restrict__ ws) {
  __shared__ float lds[32][LDP];
  float* h1b = ws + F_OFF_H1;
  float* h2b = ws + F_OFF_H2;
  unsigned* bar = (unsigned*)(ws + F_OFF_BAR);
  float* g1 = ws + F_OFF_G1;
  float* g2 = ws + F_OFF_G2;
  float* hid = ws + F_OFF_HID;
  const int tid = threadIdx.x;
  const int wg = blockIdx.x;
  const int xcd = wg & 7, grp = wg >> 3;
  const int m_blk = grp >> 2, n_blk = (xcd << 2) | (grp & 3);
  const int row0 = m_blk * 32;
  const int rowA = tid & 31, cq = tid >> 5;
  const int nrow = row0 + rowA;
  for (int t = 0; t <= T_; ++t) {
    const int p = t & 1;
    const float* h1o = h1b + (size_t)p * F_SZ_H;
    float* h1n = h1b + (size_t)(p ^ 1) * F_SZ_H;
    const float* h2o = h2b + (size_t)p * F_SZ_H;
    float* h2n = h2b + (size_t)(p ^ 1) * F_SZ_H;
    if (t < T_) {
      float2 acc = {0.f, 0.f};
      const int col = n_blk * 32 + cq * 2;
      stage<64, false>(lds, frames, T_ * C_, t * C_, nullptr, 0, 0, row0);
      __syncthreads();
      fma2<64>(acc, lds, rowA, Wg1 + col, 1024);
      __syncthreads();
#pragma unroll 1
      for (int ch = 0; ch < 2; ++ch) {
        stage<256, false>(lds, h1o, U_, ch * 256, nullptr, 0, 0, row0);
        __syncthreads();
        fma2<256>(acc, lds, rowA, Wg1 + (size_t)(64 + ch * 256) * 1024 + col, 1024);
        __syncthreads();
      }
      const float2 bb = *(const float2*)(bg1 + col);
      float* gp = g1 + (size_t)nrow * 1024 + col;
      gp[0] = sigmoidf_(acc.x + bb.x);
      gp[1] = sigmoidf_(acc.y + bb.y);
    }
    gbarF(bar, NWG);
    if (t < T_) {
      float acc = 0.f;
      const int col = n_blk * 16 + cq;
      stage<64, false>(lds, frames, T_ * C_, t * C_, nullptr, 0, 0, row0);
      __syncthreads();
      fma1<64>(acc, lds, rowA, Wc1 + col, U_);
      __syncthreads();
#pragma unroll 1
      for (int ch = 0; ch < 2; ++ch) {
        stage<256, true>(lds, h1o, U_, ch * 256, g1, 1024, ch * 256, row0);
        __syncthreads();
        fma1<256>(acc, lds, rowA, Wc1 + (size_t)(64 + ch * 256) * U_ + col, U_);
        __syncthreads();
      }
      const float cv = tanhf_(acc + bc1[col]);
      const float u = g1[(size_t)nrow * 1024 + 512 + col];
      const float ho = h1o[(size_t)nrow * U_ + col];
      h1n[(size_t)nrow * U_ + col] = u * ho + (1.f - u) * cv;
    }
    if (t > 0) {
      float acc = 0.f;
      const int col = n_blk * 8 + (cq & 7);
      const bool act = tid < 256;
#pragma unroll 1
      for (int ch = 0; ch < 2; ++ch) {
        stage<256, false>(lds, h2o, U_, ch * 256, nullptr, 0, 0, row0);
        __syncthreads();
        if (act) fma1<256>(acc, lds, rowA, Wh + (size_t)(ch * 256) * H_ + col, H_);
        __syncthreads();
      }
      if (act) {
        const float z = acc + bh[col];
        hid[(size_t)nrow * H_ + col] = z > 0.f ? z : __expf(z) - 1.f;
      }
    }
    gbarF(bar, NWG);
    if (t < T_) {
      float2 acc = {0.f, 0.f};
      const int col = n_blk * 32 + cq * 2;
#pragma unroll 1
      for (int ch = 0; ch < 4; ++ch) {
        const float* src = (ch < 2) ? h1n : h2o;
        stage<256, false>(lds, src, U_, (ch & 1) * 256, nullptr, 0, 0, row0);
        __syncthreads();
        fma2<256>(acc, lds, rowA, Wg2 + (size_t)(ch * 256) * 1024 + col, 1024);
        __syncthreads();
      }
      const float2 bb = *(const float2*)(bg2 + col);
      float* gp = g2 + (size_t)nrow * 1024 + col;
      gp[0] = sigmoidf_(acc.x + bb.x);
      gp[1] = sigmoidf_(acc.y + bb.y);
    }
    gbarF(bar, NWG);
    if (t < T_) {
      float acc = 0.f;
      const int col = n_blk * 16 + cq;
#pragma unroll 1
      for (int ch = 0; ch < 4; ++ch) {
        if (ch < 2) stage<256, false>(lds, h1n, U_, (ch & 1) * 256, nullptr, 0, 0, row0);
        else stage<256, true>(lds, h2o, U_, (ch & 1) * 256, g2, 1024, (ch & 1) * 256, row0);
        __syncthreads();
        fma1<256>(acc, lds, rowA, Wc2 + (size_t)(ch * 256) * U_ + col, U_);
        __syncthreads();
      }
      const float cv = tanhf_(acc + bc2[col]);
      const float u = g2[(size_t)nrow * 1024 + 512 + col];
      const float ho = h2o[(size_t)nrow * U_ + col];
      h2n[(size_t)nrow * U_ + col] = u * ho + (1.f - u) * cv;
    }
    if (t > 0) {
      if (tid < 64) {
        float acc = 0.f;
        const int col = n_blk * 2 + cq;
        const float* hrow = hid + (size_t)nrow * H_;
#pragma unroll 8
        for (int k = 0; k < H_; ++k) acc = fmaf(hrow[k], Wp[(size_t)k * C_ + col], acc);
        out[(size_t)nrow * (T_ * C_) + (size_t)(t - 1) * C_ + col] = acc + bp[col];
      }
    }
  }
}

// ---------------- launch ---------------------------------------------------
extern "C" void kernel_launch(void* const* d_in, const int* in_sizes, int n_in,
                              void* d_out, int out_size, void* d_ws, size_t ws_size,
                              hipStream_t stream) {
  const float* frames = (const float*)d_in[0];
  const float* Wg1 = (const float*)d_in[1];
  const float* bg1 = (const float*)d_in[2];
  const float* Wc1 = (const float*)d_in[3];
  const float* bc1 = (const float*)d_in[4];
  const float* Wg2 = (const float*)d_in[5];
  const float* bg2 = (const float*)d_in[6];
  const float* Wc2 = (const float*)d_in[7];
  const float* bc2 = (const float*)d_in[8];
  const float* Wh = (const float*)d_in[9];
  const float* bh = (const float*)d_in[10];
  const float* Wp = (const float*)d_in[11];
  const float* bp = (const float*)d_in[12];
  float* out = (float*)d_out;

  if (ws_size >= WS_NEED) {
    char* wsb = (char*)d_ws;
    // zero barrier area + h-plane buffer 0
    hipMemsetAsync(d_ws, 0, 2048 + 4 * HPB, stream);
    void* args[] = {(void*)&frames, (void*)&Wg1, (void*)&bg1, (void*)&Wc1, (void*)&bc1,
                    (void*)&Wg2, (void*)&bg2, (void*)&Wc2, (void*)&bc2,
                    (void*)&Wh, (void*)&bh, (void*)&Wp, (void*)&bp,
                    (void*)&out, (void*)&wsb};
    hipError_t err = hipLaunchCooperativeKernel((const void*)gru_mfma,
                                                dim3(NWG), dim3(TPB), args, 0, stream);
    if (err != hipSuccess) {
      (void)hipGetLastError();
      hipLaunchKernelGGL(gru_mfma, dim3(NWG), dim3(TPB), 0, stream,
                         frames, Wg1, bg1, Wc1, bc1, Wg2, bg2, Wc2, bc2,
                         Wh, bh, Wp, bp, out, wsb);
    }
  } else {
    float* ws = (float*)d_ws;
    hipMemsetAsync(d_ws, 0, F_OFF_G1 * sizeof(float), stream);
    void* args[] = {(void*)&frames, (void*)&Wg1, (void*)&bg1, (void*)&Wc1, (void*)&bc1,
                    (void*)&Wg2, (void*)&bg2, (void*)&Wc2, (void*)&bc2,
                    (void*)&Wh, (void*)&bh, (void*)&Wp, (void*)&bp,
                    (void*)&out, (void*)&ws};
    hipError_t err = hipLaunchCooperativeKernel((const void*)gru_persistent,
                                                dim3(NWG), dim3(TPB), args, 0, stream);
    if (err != hipSuccess) {
      (void)hipGetLastError();
      hipLaunchKernelGGL(gru_persistent, dim3(NWG), dim3(TPB), 0, stream,
                         frames, Wg1, bg1, Wc1, bc1, Wg2, bg2, Wc2, bc2,
                         Wh, bh, Wp, bp, out, ws);
    }
  }
}

// Round 5
// 5345.296 us; speedup vs baseline: 6.3174x; 1.0342x over previous
//
#include <hip/hip_runtime.h>
#include <cstdint>
#include <cstddef>

// ---------------------------------------------------------------------------
// VWFutureModel: 2-layer GRU scan (T=128, N=256, C=64, U=512) + dense head.
// R5: pipelined coherent access via raw asm (sc0 sc1) instead of serialized
//     __hip_atomic loads/stores.
//  - mm_core: issue ALL A-fragment coherent loads, ONE vmcnt(0)+sched_barrier,
//    then MFMA loop (B from L2-resident swizzled streams, plain loads)
//  - epilogues: batched coherent loads (single waitcnt inside asm block),
//    fire-and-forget coherent stores drained once at the group barrier
//  - phase pairs (P2|P2b, P4|P4b) share one sync slot, separate red regions
//  - weight streams zero-padded -> branchless slot loops
//  - fence-free group barriers (R4-proven); fenced barrier only in prologue
// ---------------------------------------------------------------------------

#define NWG 256
#define TPB 512

constexpr int N_ = 256, T_ = 128, C_ = 64, U_ = 512, H_ = 256;

typedef __attribute__((ext_vector_type(8))) short short8;
typedef __attribute__((ext_vector_type(4))) float f32x4;
typedef __attribute__((ext_vector_type(4))) unsigned int u32x4;
typedef __attribute__((ext_vector_type(2))) unsigned int u32x2;

// ---------------- byte offsets in workspace (MFMA kernel) ------------------
constexpr size_t HPB      = 262144;                 // one h plane: 256*512*2B
constexpr size_t OFF_BAR  = 0;                      // 2048 B barrier area
constexpr size_t OFF_HP   = 2048;                   // 2 bufs x [h1hi,h1lo,h2hi,h2lo]
constexpr size_t OFF_RH1  = OFF_HP + 8 * HPB;
constexpr size_t OFF_RH2  = OFF_RH1 + 524288;
constexpr size_t OFF_G1U  = OFF_RH2 + 524288;       // fp32 [256][512]
constexpr size_t OFF_G2U  = OFF_G1U + 524288;
constexpr size_t OFF_HID  = OFF_G2U + 524288;       // hid hi,lo (2*131072)
constexpr size_t OFF_XHI  = OFF_HID + 262144;       // [256][8192] bf16
constexpr size_t OFF_XLO  = OFF_XHI + 4194304;
constexpr size_t OFF_WG1S = OFF_XLO + 4194304;      // 32 * 81920
constexpr size_t OFF_WC1S = OFF_WG1S + 32 * 81920;  // 32 * 40960
constexpr size_t OFF_WG2S = OFF_WC1S + 32 * 40960;  // 32 * 131072
constexpr size_t OFF_WC2S = OFF_WG2S + 32 * 131072; // 32 * 65536
constexpr size_t OFF_WHS  = OFF_WC2S + 32 * 65536;  // 16 * 32768
constexpr size_t OFF_WPS  = OFF_WHS + 16 * 32768;   // 4 * 16384
constexpr size_t WS_NEED  = OFF_WPS + 4 * 16384;    // ~23.7 MB

// ---------------- scalar helpers -------------------------------------------
__device__ __forceinline__ float sigmoidf_(float z) {
  return 1.0f / (1.0f + __expf(-z));
}
__device__ __forceinline__ float tanhf_(float z) {
  return 1.0f - 2.0f / (1.0f + __expf(2.0f * z));
}
__device__ __forceinline__ unsigned short bf_hi(float f) {
  unsigned int x = __float_as_uint(f);
  unsigned int r = x + 0x7FFFu + ((x >> 16) & 1u);
  return (unsigned short)(r >> 16);
}
__device__ __forceinline__ float bf_f(unsigned v) {  // low 16 bits as bf16
  return __uint_as_float((v & 0xFFFFu) << 16);
}
__device__ __forceinline__ float bf_fh(unsigned v) {  // high 16 bits as bf16
  return __uint_as_float(v & 0xFFFF0000u);
}
__device__ __forceinline__ unsigned short bf_lo(float f, unsigned short hi) {
  return bf_hi(f - __uint_as_float(((unsigned)hi) << 16));
}

// ---------------- pipelined coherent access (raw asm, sc0 sc1) -------------
// Loads: issued without waits; caller (or the asm block itself) drains vmcnt.
__device__ __forceinline__ u32x4 ldc_b128(const void* p) {
  u32x4 r;
  asm volatile("global_load_dwordx4 %0, %1, off sc0 sc1" : "=&v"(r) : "v"(p));
  return r;
}
// Batched epilogue loads: single waitcnt INSIDE the asm (outputs safe at end).
__device__ __forceinline__ void ldc2_b32(const void* p0, const void* p1,
                                         unsigned& a, unsigned& b) {
  asm volatile("global_load_dword %0, %2, off sc0 sc1\n\t"
               "global_load_dword %1, %3, off sc0 sc1\n\t"
               "s_waitcnt vmcnt(0)"
               : "=&v"(a), "=&v"(b) : "v"(p0), "v"(p1));
}
__device__ __forceinline__ void ldc3(const void* pq, const void* p0, const void* p1,
                                     u32x2& q, unsigned& a, unsigned& b) {
  asm volatile("global_load_dwordx2 %0, %3, off sc0 sc1\n\t"
               "global_load_dword %1, %4, off sc0 sc1\n\t"
               "global_load_dword %2, %5, off sc0 sc1\n\t"
               "s_waitcnt vmcnt(0)"
               : "=&v"(q), "=&v"(a), "=&v"(b) : "v"(pq), "v"(p0), "v"(p1));
}
// Stores: fire-and-forget; drained by the barrier's vmcnt(0).
__device__ __forceinline__ void stc_b32(void* p, unsigned v) {
  asm volatile("global_store_dword %0, %1, off sc0 sc1" :: "v"(p), "v"(v) : "memory");
}
__device__ __forceinline__ void stc_b64(void* p, u32x2 v) {
  asm volatile("global_store_dwordx2 %0, %1, off sc0 sc1" :: "v"(p), "v"(v) : "memory");
}

// ---------------- barriers -------------------------------------------------
// Fence-free group barrier (R4-proven): drain vmcnt (coherent stores reach the
// coherence point), then relaxed agent-scope arrive + epoch poll.
__device__ __forceinline__ void gbarN(unsigned* b, unsigned np) {
  asm volatile("s_waitcnt vmcnt(0) lgkmcnt(0)" ::: "memory");
  __syncthreads();
  if (threadIdx.x == 0) {
    unsigned e = __hip_atomic_load(b + 16, __ATOMIC_RELAXED, __HIP_MEMORY_SCOPE_AGENT);
    unsigned a = __hip_atomic_fetch_add(b, 1u, __ATOMIC_RELAXED, __HIP_MEMORY_SCOPE_AGENT);
    if (a == np - 1) {
      __hip_atomic_store(b, 0u, __ATOMIC_RELAXED, __HIP_MEMORY_SCOPE_AGENT);
      __hip_atomic_store(b + 16, e + 1u, __ATOMIC_RELAXED, __HIP_MEMORY_SCOPE_AGENT);
    } else {
      unsigned spins = 0;
      while (__hip_atomic_load(b + 16, __ATOMIC_RELAXED, __HIP_MEMORY_SCOPE_AGENT) == e) {
        __builtin_amdgcn_s_sleep(1);
        if (++spins > (1u << 20)) break;  // escape hatch: fail, don't hang
      }
    }
  }
  __syncthreads();
}

// Fully-fenced barrier (prologue + fallback kernel).
__device__ __forceinline__ void gbarF(unsigned* b, unsigned np) {
  __syncthreads();
  if (threadIdx.x == 0) {
    __threadfence();
    unsigned e = __hip_atomic_load(b + 16, __ATOMIC_RELAXED, __HIP_MEMORY_SCOPE_AGENT);
    unsigned a = __hip_atomic_fetch_add(b, 1u, __ATOMIC_ACQ_REL, __HIP_MEMORY_SCOPE_AGENT);
    if (a == np - 1) {
      __hip_atomic_store(b, 0u, __ATOMIC_RELAXED, __HIP_MEMORY_SCOPE_AGENT);
      __hip_atomic_store(b + 16, e + 1u, __ATOMIC_RELEASE, __HIP_MEMORY_SCOPE_AGENT);
    } else {
      unsigned spins = 0;
      while (__hip_atomic_load(b + 16, __ATOMIC_RELAXED, __HIP_MEMORY_SCOPE_AGENT) == e) {
        __builtin_amdgcn_s_sleep(1);
        if (++spins > (1u << 20)) break;
      }
    }
    __threadfence();
  }
  __syncthreads();
}

// ---------------- weight stream swizzle (prologue) -------------------------
// Zero-pads slots with c >= nch so the steady-state slot loop is branchless.
__device__ void writeStream(const float* __restrict__ W, int ldW, int colbase,
                            char* sb, int nsplit, int slots, int tnn, int nch) {
  const int tid = threadIdx.x;
  const int lane = tid & 63;
  const int e = tid >> 6;  // 0..7
  const int nf = nsplit * slots * tnn;
  for (int f = 0; f < nf; ++f) {
    int tn = f % tnn;
    int ci = (f / tnn) % slots;
    int ks = f / (tnn * slots);
    int c = ks + ci * nsplit;
    int k = 32 * c + ((lane >> 4) << 3) + e;
    int col = colbase + 16 * tn + (lane & 15);
    float v = (c < nch) ? W[(size_t)k * ldW + col] : 0.f;
    unsigned short hi = bf_hi(v);
    unsigned short lo = bf_lo(v, hi);
    unsigned short* fb = (unsigned short*)(sb + (size_t)f * 2048);
    fb[lane * 8 + e] = hi;
    fb[512 + lane * 8 + e] = lo;
  }
}

// ---------------- MFMA core (no internal syncs) ----------------------------
// Pass 1: issue ALL coherent A loads; one vmcnt(0)+sched_barrier.
// Pass 2: B loads (plain, L2) + 3-term split-bf16 MFMAs. Writes red partials.
template <int TM, int TN, int NSPLIT, int SLOTS, int KA>
__device__ __forceinline__ void mm_core(
    const unsigned short* __restrict__ A1h, const unsigned short* __restrict__ A1l,
    int lda1, int aoff,
    const unsigned short* __restrict__ A2h, const unsigned short* __restrict__ A2l,
    int lda2, const char* __restrict__ bstr, float* red, int row0loc) {
  const int tid = threadIdx.x;
  const int ww = tid >> 6, lane = tid & 63;
  const int tm = ww / NSPLIT;
  const int ks = ww % NSPLIT;
  const int arow = row0loc + 16 * tm + (lane & 15);
  const int kgrp = (lane >> 4) << 3;

  u32x4 Ah[SLOTS], Al[SLOTS];
#pragma unroll
  for (int ci = 0; ci < SLOTS; ++ci) {
    const int c = ks + ci * NSPLIT;
    const int ak = 32 * c + kgrp;
    const unsigned short *ph, *pl;
    if (ak < KA) {
      ph = A1h + (size_t)arow * lda1 + aoff + ak;
      pl = A1l + (size_t)arow * lda1 + aoff + ak;
    } else {
      const int ak2 = ak - KA;
      ph = A2h + (size_t)arow * lda2 + ak2;
      pl = A2l + (size_t)arow * lda2 + ak2;
    }
    Ah[ci] = ldc_b128(ph);
    Al[ci] = ldc_b128(pl);
  }
  asm volatile("s_waitcnt vmcnt(0)" ::: "memory");
  __builtin_amdgcn_sched_barrier(0);  // rule #18: pin MFMAs after the wait

  f32x4 acc0[TN], acc1[TN], acc2[TN];
#pragma unroll
  for (int tn = 0; tn < TN; ++tn) {
    acc0[tn] = (f32x4){0.f, 0.f, 0.f, 0.f};
    acc1[tn] = (f32x4){0.f, 0.f, 0.f, 0.f};
    acc2[tn] = (f32x4){0.f, 0.f, 0.f, 0.f};
  }
#pragma unroll
  for (int ci = 0; ci < SLOTS; ++ci) {
    union { u32x4 u; short8 s; } ah, al;
    ah.u = Ah[ci]; al.u = Al[ci];
    const char* fb = bstr + ((size_t)(ks * SLOTS + ci) * TN) * 2048;
#pragma unroll
    for (int tn = 0; tn < TN; ++tn) {
      union { uint4 u; short8 s; } bh, bl;
      bh.u = *(const uint4*)((const unsigned short*)(fb + (size_t)tn * 2048) + lane * 8);
      bl.u = *(const uint4*)((const unsigned short*)(fb + (size_t)tn * 2048 + 1024) + lane * 8);
      acc0[tn] = __builtin_amdgcn_mfma_f32_16x16x32_bf16(ah.s, bh.s, acc0[tn], 0, 0, 0);
      acc1[tn] = __builtin_amdgcn_mfma_f32_16x16x32_bf16(ah.s, bl.s, acc1[tn], 0, 0, 0);
      acc2[tn] = __builtin_amdgcn_mfma_f32_16x16x32_bf16(al.s, bh.s, acc2[tn], 0, 0, 0);
    }
  }
#pragma unroll
  for (int tn = 0; tn < TN; ++tn) {
    f32x4 s = acc0[tn] + acc1[tn] + acc2[tn];
    int slot = (tm * TN + tn) * NSPLIT + ks;
    *(f32x4*)(&red[slot * 256 + lane * 4]) = s;
  }
}

// reduce partials + run epilogue per COLUMN-PAIR (col, col+1)
template <int TM, int TN, int NSPLIT, typename F>
__device__ __forceinline__ void epi2(const float* red, int row0loc, int col0, F f) {
  for (int idx = threadIdx.x; idx < TM * TN * 128; idx += TPB) {
    int tg = idx >> 7;
    int r  = (idx >> 3) & 15;
    int cp = idx & 7;
    int e0 = (((((r >> 2) << 4) | (cp << 1)) << 2) | (r & 3));
    float z0 = 0.f, z1 = 0.f;
#pragma unroll
    for (int s = 0; s < NSPLIT; ++s) {
      const float* rp = red + (tg * NSPLIT + s) * 256;
      z0 += rp[e0];
      z1 += rp[e0 + 4];
    }
    int tm = tg / TN, tn = tg % TN;
    f(row0loc + 16 * tm + r, col0 + 16 * tn + cp * 2, z0, z1);
  }
}

// ---------------- MFMA kernel ----------------------------------------------
extern "C" __global__ __launch_bounds__(TPB, 2)
void gru_mfma(const float* __restrict__ frames,
              const float* __restrict__ Wg1, const float* __restrict__ bg1,
              const float* __restrict__ Wc1, const float* __restrict__ bc1,
              const float* __restrict__ Wg2, const float* __restrict__ bg2,
              const float* __restrict__ Wc2, const float* __restrict__ bc2,
              const float* __restrict__ Wh,  const float* __restrict__ bh,
              const float* __restrict__ Wp,  const float* __restrict__ bp,
              float* __restrict__ out, char* __restrict__ wsb) {
  __shared__ float red[4096];  // 16 KB: [0..2047] primary, [2048..4095] pair

  const int tid = threadIdx.x;
  const int wg = blockIdx.x;
  const int xcd = wg & 7;
  const int grp = wg >> 3;
  const int m = grp >> 2;                 // 0..7  row group (rows 32m..32m+31)
  const int n = (xcd << 2) | (grp & 3);   // 0..31 col slice (XCD-local weights)
  const int row0 = m * 32;

  unsigned* barw = (unsigned*)(wsb + OFF_BAR);
  unsigned* gb = barw + m * 32;    // per-group barrier
  unsigned* allb = barw + 256;     // global barrier (prologue only)

  unsigned short* xhi = (unsigned short*)(wsb + OFF_XHI);
  unsigned short* xlo = (unsigned short*)(wsb + OFF_XLO);
  unsigned short* rh1hi = (unsigned short*)(wsb + OFF_RH1);
  unsigned short* rh1lo = (unsigned short*)(wsb + OFF_RH1 + 262144);
  unsigned short* rh2hi = (unsigned short*)(wsb + OFF_RH2);
  unsigned short* rh2lo = (unsigned short*)(wsb + OFF_RH2 + 262144);
  float* g1u = (float*)(wsb + OFF_G1U);
  float* g2u = (float*)(wsb + OFF_G2U);
  unsigned short* hidhi = (unsigned short*)(wsb + OFF_HID);
  unsigned short* hidlo = (unsigned short*)(wsb + OFF_HID + 131072);

  // ---- prologue: x planes (normal stores; fenced barrier below) ----
  {
    const size_t base = (size_t)wg * 8192;
    for (int i = tid; i < 8192; i += TPB) {
      float v = frames[base + i];
      unsigned short h = bf_hi(v);
      xhi[base + i] = h;
      xlo[base + i] = bf_lo(v, h);
    }
  }
  // ---- prologue: weight streams ----
  if (m == 0) {
    writeStream(Wg1, 1024, n * 32, wsb + OFF_WG1S + (size_t)n * 81920, 4, 5, 2, 18);
    writeStream(Wc1, 512, n * 16, wsb + OFF_WC1S + (size_t)n * 40960, 4, 5, 1, 18);
    writeStream(Wg2, 1024, n * 32, wsb + OFF_WG2S + (size_t)n * 131072, 4, 8, 2, 32);
    writeStream(Wc2, 512, n * 16, wsb + OFF_WC2S + (size_t)n * 65536, 4, 8, 1, 32);
  }
  if (wg < 16) writeStream(Wh, 256, wg * 16, wsb + OFF_WHS + (size_t)wg * 32768, 8, 2, 1, 16);
  if (wg < 4)  writeStream(Wp, 64, wg * 16, wsb + OFF_WPS + (size_t)wg * 16384, 8, 1, 1, 8);
  gbarF(allb, NWG);  // fenced: publish x + weights device-wide, once

  const char* wg1s = (const char*)(wsb + OFF_WG1S + (size_t)n * 81920);
  const char* wc1s = (const char*)(wsb + OFF_WC1S + (size_t)n * 40960);
  const char* wg2s = (const char*)(wsb + OFF_WG2S + (size_t)n * 131072);
  const char* wc2s = (const char*)(wsb + OFF_WC2S + (size_t)n * 65536);
  const int b2 = n & 15, a2 = n >> 4;            // P2b tile within group
  const int b4 = n & 3, a4 = (n >> 2) & 1;       // P4b tile (n<8 active)
  const char* whs = (const char*)(wsb + OFF_WHS + (size_t)b2 * 32768);
  const char* wps = (const char*)(wsb + OFF_WPS + (size_t)b4 * 16384);

  for (int t = 0; t <= T_; ++t) {
    const int p = t & 1, q = p ^ 1;
    unsigned short* h1hi_p = (unsigned short*)(wsb + OFF_HP + (size_t)p * 4 * HPB);
    unsigned short* h1lo_p = h1hi_p + 131072;
    unsigned short* h2hi_p = h1hi_p + 262144;
    unsigned short* h2lo_p = h1hi_p + 393216;
    unsigned short* h1hi_q = (unsigned short*)(wsb + OFF_HP + (size_t)q * 4 * HPB);
    unsigned short* h1lo_q = h1hi_q + 131072;

    // ================= slot A: P1 gates1 =================
    if (t < T_) {
      mm_core<2, 2, 4, 5, 64>(xhi, xlo, 8192, t * 64, h1hi_p, h1lo_p, 512,
                              wg1s, red, row0);
      __syncthreads();
      epi2<2, 2, 4>(red, row0, n * 32, [&](int row, int col, float z0, float z1) {
        z0 += bg1[col]; z1 += bg1[col + 1];
        float s0 = sigmoidf_(z0), s1 = sigmoidf_(z1);
        if (col < 512) {
          size_t ix = (size_t)row * 512 + col;
          unsigned hw, lw;
          ldc2_b32(h1hi_p + ix, h1lo_p + ix, hw, lw);
          float h0 = bf_f(hw) + bf_f(lw);
          float h1v = bf_fh(hw) + bf_fh(lw);
          float r0 = s0 * h0, r1 = s1 * h1v;
          unsigned short a0 = bf_hi(r0), a1 = bf_hi(r1);
          stc_b32(rh1hi + ix, (unsigned)a0 | ((unsigned)a1 << 16));
          stc_b32(rh1lo + ix, (unsigned)bf_lo(r0, a0) | ((unsigned)bf_lo(r1, a1) << 16));
        } else {
          u32x2 g = {__float_as_uint(s0), __float_as_uint(s1)};
          stc_b64(g1u + (size_t)row * 512 + (col - 512), g);
        }
      });
    }
    gbarN(gb, 32);

    // ================= slot B: P2 cand1 | P2b head-dense =================
    if (t < T_)
      mm_core<2, 1, 4, 5, 64>(xhi, xlo, 8192, t * 64, rh1hi, rh1lo, 512,
                              wc1s, red, row0);
    if (t > 0)
      mm_core<1, 1, 8, 2, 512>(h2hi_p, h2lo_p, 512, 0, nullptr, nullptr, 0,
                               whs, red + 2048, row0 + 16 * a2);
    __syncthreads();
    if (t < T_) {
      epi2<2, 1, 4>(red, row0, n * 16, [&](int row, int col, float z0, float z1) {
        z0 += bc1[col]; z1 += bc1[col + 1];
        float c0 = tanhf_(z0), c1 = tanhf_(z1);
        size_t ix = (size_t)row * 512 + col;
        u32x2 ug; unsigned hw, lw;
        ldc3(g1u + ix, h1hi_p + ix, h1lo_p + ix, ug, hw, lw);
        float u0 = __uint_as_float(ug.x), u1 = __uint_as_float(ug.y);
        float h0 = bf_f(hw) + bf_f(lw);
        float h1v = bf_fh(hw) + bf_fh(lw);
        float n0 = u0 * h0 + (1.f - u0) * c0;
        float n1 = u1 * h1v + (1.f - u1) * c1;
        unsigned short a0 = bf_hi(n0), a1 = bf_hi(n1);
        stc_b32(h1hi_q + ix, (unsigned)a0 | ((unsigned)a1 << 16));
        stc_b32(h1lo_q + ix, (unsigned)bf_lo(n0, a0) | ((unsigned)bf_lo(n1, a1) << 16));
      });
    }
    if (t > 0) {
      epi2<1, 1, 8>(red + 2048, row0 + 16 * a2, 16 * b2,
                    [&](int row, int col, float z0, float z1) {
        z0 += bh[col]; z1 += bh[col + 1];
        float e0v = z0 > 0.f ? z0 : __expf(z0) - 1.f;
        float e1v = z1 > 0.f ? z1 : __expf(z1) - 1.f;
        size_t ix = (size_t)row * 256 + col;
        unsigned short a0 = bf_hi(e0v), a1 = bf_hi(e1v);
        stc_b32(hidhi + ix, (unsigned)a0 | ((unsigned)a1 << 16));
        stc_b32(hidlo + ix, (unsigned)bf_lo(e0v, a0) | ((unsigned)bf_lo(e1v, a1) << 16));
      });
    }
    gbarN(gb, 32);

    // ================= slot C: P3 gates2 =================
    if (t < T_) {
      mm_core<2, 2, 4, 8, 512>(h1hi_q, h1lo_q, 512, 0, h2hi_p, h2lo_p, 512,
                               wg2s, red, row0);
      __syncthreads();
      epi2<2, 2, 4>(red, row0, n * 32, [&](int row, int col, float z0, float z1) {
        z0 += bg2[col]; z1 += bg2[col + 1];
        float s0 = sigmoidf_(z0), s1 = sigmoidf_(z1);
        if (col < 512) {
          size_t ix = (size_t)row * 512 + col;
          unsigned hw, lw;
          ldc2_b32(h2hi_p + ix, h2lo_p + ix, hw, lw);
          float h0 = bf_f(hw) + bf_f(lw);
          float h1v = bf_fh(hw) + bf_fh(lw);
          float r0 = s0 * h0, r1 = s1 * h1v;
          unsigned short a0 = bf_hi(r0), a1 = bf_hi(r1);
          stc_b32(rh2hi + ix, (unsigned)a0 | ((unsigned)a1 << 16));
          stc_b32(rh2lo + ix, (unsigned)bf_lo(r0, a0) | ((unsigned)bf_lo(r1, a1) << 16));
        } else {
          u32x2 g = {__float_as_uint(s0), __float_as_uint(s1)};
          stc_b64(g2u + (size_t)row * 512 + (col - 512), g);
        }
      });
    }
    gbarN(gb, 32);

    // ================= slot D: P4 cand2 | P4b out-proj =================
    {
      unsigned short* h2hi_q = h1hi_q + 262144;
      unsigned short* h2lo_q = h1hi_q + 393216;
      if (t < T_)
        mm_core<2, 1, 4, 8, 512>(h1hi_q, h1lo_q, 512, 0, rh2hi, rh2lo, 512,
                                 wc2s, red, row0);
      if (t > 0 && n < 8)
        mm_core<1, 1, 8, 1, 256>(hidhi, hidlo, 256, 0, nullptr, nullptr, 0,
                                 wps, red + 2048, row0 + 16 * a4);
      __syncthreads();
      if (t < T_) {
        epi2<2, 1, 4>(red, row0, n * 16, [&](int row, int col, float z0, float z1) {
          z0 += bc2[col]; z1 += bc2[col + 1];
          float c0 = tanhf_(z0), c1 = tanhf_(z1);
          size_t ix = (size_t)row * 512 + col;
          u32x2 ug; unsigned hw, lw;
          ldc3(g2u + ix, h2hi_p + ix, h2lo_p + ix, ug, hw, lw);
          float u0 = __uint_as_float(ug.x), u1 = __uint_as_float(ug.y);
          float h0 = bf_f(hw) + bf_f(lw);
          float h1v = bf_fh(hw) + bf_fh(lw);
          float n0 = u0 * h0 + (1.f - u0) * c0;
          float n1 = u1 * h1v + (1.f - u1) * c1;
          unsigned short a0 = bf_hi(n0), a1 = bf_hi(n1);
          stc_b32(h2hi_q + ix, (unsigned)a0 | ((unsigned)a1 << 16));
          stc_b32(h2lo_q + ix, (unsigned)bf_lo(n0, a0) | ((unsigned)bf_lo(n1, a1) << 16));
        });
      }
      if (t > 0 && n < 8) {
        epi2<1, 1, 8>(red + 2048, row0 + 16 * a4, 16 * b4,
                      [&](int row, int col, float z0, float z1) {
          float2 v = {z0 + bp[col], z1 + bp[col + 1]};
          *(float2*)(out + (size_t)row * 8192 + (size_t)(t - 1) * 64 + col) = v;
        });
      }
    }
    __syncthreads();  // protect red before next step's slot A rewrite
  }
}

// ======================= R2 fallback (proven fp32 path) ====================
constexpr size_t F_SZ_H   = (size_t)N_ * U_;
constexpr size_t F_OFF_H1 = 0;
constexpr size_t F_OFF_H2 = F_OFF_H1 + 2 * F_SZ_H;
constexpr size_t F_OFF_BAR = F_OFF_H2 + 2 * F_SZ_H;
constexpr size_t F_OFF_G1 = F_OFF_BAR + 64;
constexpr size_t F_OFF_G2 = F_OFF_G1 + (size_t)N_ * 1024;
constexpr size_t F_OFF_HID = F_OFF_G2 + (size_t)N_ * 1024;
constexpr int LDP = 257;

template <int CK, bool GATED>
__device__ __forceinline__ void stage(float (*lds)[LDP],
                                      const float* __restrict__ src, int sStride, int sOff,
                                      const float* __restrict__ gate, int gStride, int gOff,
                                      int row0) {
  constexpr int PER = CK / 16;
  const int r = threadIdx.x >> 4;
  const int c0 = (threadIdx.x & 15) * PER;
  const float* s = src + (size_t)(row0 + r) * sStride + sOff + c0;
  float4 a0, a1, a2, a3;
  a0 = *(const float4*)(s);
  if constexpr (PER >= 8) a1 = *(const float4*)(s + 4);
  if constexpr (PER >= 16) { a2 = *(const float4*)(s + 8); a3 = *(const float4*)(s + 12); }
  if constexpr (GATED) {
    const float* g = gate + (size_t)(row0 + r) * gStride + gOff + c0;
    float4 g0 = *(const float4*)(g);
    a0.x *= g0.x; a0.y *= g0.y; a0.z *= g0.z; a0.w *= g0.w;
    if constexpr (PER >= 8) {
      float4 g1v = *(const float4*)(g + 4);
      a1.x *= g1v.x; a1.y *= g1v.y; a1.z *= g1v.z; a1.w *= g1v.w;
    }
    if constexpr (PER >= 16) {
      float4 g2v = *(const float4*)(g + 8);
      float4 g3v = *(const float4*)(g + 12);
      a2.x *= g2v.x; a2.y *= g2v.y; a2.z *= g2v.z; a2.w *= g2v.w;
      a3.x *= g3v.x; a3.y *= g3v.y; a3.z *= g3v.z; a3.w *= g3v.w;
    }
  }
  float* d = &lds[r][c0];
  d[0] = a0.x; d[1] = a0.y; d[2] = a0.z; d[3] = a0.w;
  if constexpr (PER >= 8) { d[4] = a1.x; d[5] = a1.y; d[6] = a1.z; d[7] = a1.w; }
  if constexpr (PER >= 16) {
    d[8] = a2.x; d[9] = a2.y; d[10] = a2.z; d[11] = a2.w;
    d[12] = a3.x; d[13] = a3.y; d[14] = a3.z; d[15] = a3.w;
  }
}
template <int CK>
__device__ __forceinline__ void fma2(float2& acc, const float (*lds)[LDP], int row,
                                     const float* __restrict__ B, int ldB) {
#pragma unroll 8
  for (int k = 0; k < CK; ++k) {
    const float a = lds[row][k];
    const float2 b = *(const float2*)(B + (size_t)k * ldB);
    acc.x = fmaf(a, b.x, acc.x);
    acc.y = fmaf(a, b.y, acc.y);
  }
}
template <int CK>
__device__ __forceinline__ void fma1(float& acc, const float (*lds)[LDP], int row,
                                     const float* __restrict__ B, int ldB) {
#pragma unroll 8
  for (int k = 0; k < CK; ++k) acc = fmaf(lds[row][k], B[(size_t)k * ldB], acc);
}

extern "C" __global__ __launch_bounds__(TPB, 2)
void gru_persistent(const float* __restrict__ frames,
                    const float* __restrict__ Wg1, const float* __restrict__ bg1,
                    const float* __restrict__ Wc1, const float* __restrict__ bc1,
                    const float* __restrict__ Wg2, const float* __restrict__ bg2,
                    const float* __restrict__ Wc2, const float* __restrict__ bc2,
                    const float* __restrict__ Wh,  const float* __restrict__ bh,
                    const float* __restrict__ Wp,  const float* __restrict__ bp,
                    float* __restrict__ out, float* __restrict__ ws) {
  __shared__ float lds[32][LDP];
  float* h1b = ws + F_OFF_H1;
  float* h2b = ws + F_OFF_H2;
  unsigned* bar = (unsigned*)(ws + F_OFF_BAR);
  float* g1 = ws + F_OFF_G1;
  float* g2 = ws + F_OFF_G2;
  float* hid = ws + F_OFF_HID;
  const int tid = threadIdx.x;
  const int wg = blockIdx.x;
  const int xcd = wg & 7, grp = wg >> 3;
  const int m_blk = grp >> 2, n_blk = (xcd << 2) | (grp & 3);
  const int row0 = m_blk * 32;
  const int rowA = tid & 31, cq = tid >> 5;
  const int nrow = row0 + rowA;
  for (int t = 0; t <= T_; ++t) {
    const int p = t & 1;
    const float* h1o = h1b + (size_t)p * F_SZ_H;
    float* h1n = h1b + (size_t)(p ^ 1) * F_SZ_H;
    const float* h2o = h2b + (size_t)p * F_SZ_H;
    float* h2n = h2b + (size_t)(p ^ 1) * F_SZ_H;
    if (t < T_) {
      float2 acc = {0.f, 0.f};
      const int col = n_blk * 32 + cq * 2;
      stage<64, false>(lds, frames, T_ * C_, t * C_, nullptr, 0, 0, row0);
      __syncthreads();
      fma2<64>(acc, lds, rowA, Wg1 + col, 1024);
      __syncthreads();
#pragma unroll 1
      for (int ch = 0; ch < 2; ++ch) {
        stage<256, false>(lds, h1o, U_, ch * 256, nullptr, 0, 0, row0);
        __syncthreads();
        fma2<256>(acc, lds, rowA, Wg1 + (size_t)(64 + ch * 256) * 1024 + col, 1024);
        __syncthreads();
      }
      const float2 bb = *(const float2*)(bg1 + col);
      float* gp = g1 + (size_t)nrow * 1024 + col;
      gp[0] = sigmoidf_(acc.x + bb.x);
      gp[1] = sigmoidf_(acc.y + bb.y);
    }
    gbarF(bar, NWG);
    if (t < T_) {
      float acc = 0.f;
      const int col = n_blk * 16 + cq;
      stage<64, false>(lds, frames, T_ * C_, t * C_, nullptr, 0, 0, row0);
      __syncthreads();
      fma1<64>(acc, lds, rowA, Wc1 + col, U_);
      __syncthreads();
#pragma unroll 1
      for (int ch = 0; ch < 2; ++ch) {
        stage<256, true>(lds, h1o, U_, ch * 256, g1, 1024, ch * 256, row0);
        __syncthreads();
        fma1<256>(acc, lds, rowA, Wc1 + (size_t)(64 + ch * 256) * U_ + col, U_);
        __syncthreads();
      }
      const float cv = tanhf_(acc + bc1[col]);
      const float u = g1[(size_t)nrow * 1024 + 512 + col];
      const float ho = h1o[(size_t)nrow * U_ + col];
      h1n[(size_t)nrow * U_ + col] = u * ho + (1.f - u) * cv;
    }
    if (t > 0) {
      float acc = 0.f;
      const int col = n_blk * 8 + (cq & 7);
      const bool act = tid < 256;
#pragma unroll 1
      for (int ch = 0; ch < 2; ++ch) {
        stage<256, false>(lds, h2o, U_, ch * 256, nullptr, 0, 0, row0);
        __syncthreads();
        if (act) fma1<256>(acc, lds, rowA, Wh + (size_t)(ch * 256) * H_ + col, H_);
        __syncthreads();
      }
      if (act) {
        const float z = acc + bh[col];
        hid[(size_t)nrow * H_ + col] = z > 0.f ? z : __expf(z) - 1.f;
      }
    }
    gbarF(bar, NWG);
    if (t < T_) {
      float2 acc = {0.f, 0.f};
      const int col = n_blk * 32 + cq * 2;
#pragma unroll 1
      for (int ch = 0; ch < 4; ++ch) {
        const float* src = (ch < 2) ? h1n : h2o;
        stage<256, false>(lds, src, U_, (ch & 1) * 256, nullptr, 0, 0, row0);
        __syncthreads();
        fma2<256>(acc, lds, rowA, Wg2 + (size_t)(ch * 256) * 1024 + col, 1024);
        __syncthreads();
      }
      const float2 bb = *(const float2*)(bg2 + col);
      float* gp = g2 + (size_t)nrow * 1024 + col;
      gp[0] = sigmoidf_(acc.x + bb.x);
      gp[1] = sigmoidf_(acc.y + bb.y);
    }
    gbarF(bar, NWG);
    if (t < T_) {
      float acc = 0.f;
      const int col = n_blk * 16 + cq;
#pragma unroll 1
      for (int ch = 0; ch < 4; ++ch) {
        if (ch < 2) stage<256, false>(lds, h1n, U_, (ch & 1) * 256, nullptr, 0, 0, row0);
        else stage<256, true>(lds, h2o, U_, (ch & 1) * 256, g2, 1024, (ch & 1) * 256, row0);
        __syncthreads();
        fma1<256>(acc, lds, rowA, Wc2 + (size_t)(ch * 256) * U_ + col, U_);
        __syncthreads();
      }
      const float cv = tanhf_(acc + bc2[col]);
      const float u = g2[(size_t)nrow * 1024 + 512 + col];
      const float ho = h2o[(size_t)nrow * U_ + col];
      h2n[(size_t)nrow * U_ + col] = u * ho + (1.f - u) * cv;
    }
    if (t > 0) {
      if (tid < 64) {
        float acc = 0.f;
        const int col = n_blk * 2 + cq;
        const float* hrow = hid + (size_t)nrow * H_;
#pragma unroll 8
        for (int k = 0; k < H_; ++k) acc = fmaf(hrow[k], Wp[(size_t)k * C_ + col], acc);
        out[(size_t)nrow * (T_ * C_) + (size_t)(t - 1) * C_ + col] = acc + bp[col];
      }
    }
  }
}

// ---------------- launch ---------------------------------------------------
extern "C" void kernel_launch(void* const* d_in, const int* in_sizes, int n_in,
                              void* d_out, int out_size, void* d_ws, size_t ws_size,
                              hipStream_t stream) {
  const float* frames = (const float*)d_in[0];
  const float* Wg1 = (const float*)d_in[1];
  const float* bg1 = (const float*)d_in[2];
  const float* Wc1 = (const float*)d_in[3];
  const float* bc1 = (const float*)d_in[4];
  const float* Wg2 = (const float*)d_in[5];
  const float* bg2 = (const float*)d_in[6];
  const float* Wc2 = (const float*)d_in[7];
  const float* bc2 = (const float*)d_in[8];
  const float* Wh = (const float*)d_in[9];
  const float* bh = (const float*)d_in[10];
  const float* Wp = (const float*)d_in[11];
  const float* bp = (const float*)d_in[12];
  float* out = (float*)d_out;

  if (ws_size >= WS_NEED) {
    char* wsb = (char*)d_ws;
    // zero barrier area + h-plane buffer 0
    hipMemsetAsync(d_ws, 0, 2048 + 4 * HPB, stream);
    void* args[] = {(void*)&frames, (void*)&Wg1, (void*)&bg1, (void*)&Wc1, (void*)&bc1,
                    (void*)&Wg2, (void*)&bg2, (void*)&Wc2, (void*)&bc2,
                    (void*)&Wh, (void*)&bh, (void*)&Wp, (void*)&bp,
                    (void*)&out, (void*)&wsb};
    hipError_t err = hipLaunchCooperativeKernel((const void*)gru_mfma,
                                                dim3(NWG), dim3(TPB), args, 0, stream);
    if (err != hipSuccess) {
      (void)hipGetLastError();
      hipLaunchKernelGGL(gru_mfma, dim3(NWG), dim3(TPB), 0, stream,
                         frames, Wg1, bg1, Wc1, bc1, Wg2, bg2, Wc2, bc2,
                         Wh, bh, Wp, bp, out, wsb);
    }
  } else {
    float* ws = (float*)d_ws;
    hipMemsetAsync(d_ws, 0, F_OFF_G1 * sizeof(float), stream);
    void* args[] = {(void*)&frames, (void*)&Wg1, (void*)&bg1, (void*)&Wc1, (void*)&bc1,
                    (void*)&Wg2, (void*)&bg2, (void*)&Wc2, (void*)&bc2,
                    (void*)&Wh, (void*)&bh, (void*)&Wp, (void*)&bp,
                    (void*)&out, (void*)&ws};
    hipError_t err = hipLaunchCooperativeKernel((const void*)gru_persistent,
                                                dim3(NWG), dim3(TPB), args, 0, stream);
    if (err != hipSuccess) {
      (void)hipGetLastError();
      hipLaunchKernelGGL(gru_persistent, dim3(NWG), dim3(TPB), 0, stream,
                         frames, Wg1, bg1, Wc1, bc1, Wg2, bg2, Wc2, bc2,
                         Wh, bh, Wp, bp, out, ws);
    }
  }
}